// Round 10
// baseline (234.496 us; speedup 1.0000x reference)
//
#include <hip/hip_runtime.h>

#define B_DIM 4
#define T_DIM 300
#define U_DIM 80
#define UP1   81
#define V_DIM 1024
#define NINNER 512
#define NROWS (B_DIM * T_DIM * UP1)   /* 97200 */
#define EP_ROWS (B_DIM * T_DIM)       /* 1200 */
#define DP_ROWS (B_DIM * UP1)         /* 324 */
#define NDIAG_B 380                    /* t+u diagonals for lpb */
#define NDIAG_E 379                    /* t+u diagonals for lpe */
#define DSTRIDE 82                     /* padded diag-row stride (floats) */
#define WF_PART 163840                 /* 512 cols x 320 k, per half of Wf */
#define LOG2E 1.44269504088896341f
#define LN2   0.69314718055994531f
#define NEGF  -1e30f

typedef float f32x4 __attribute__((ext_vector_type(4)));
typedef short short8 __attribute__((ext_vector_type(8)));
typedef short short4v __attribute__((ext_vector_type(4)));
typedef __bf16 bf16x8 __attribute__((ext_vector_type(8)));

static __device__ __forceinline__ short f2bf(float f) {
  return (short)__builtin_bit_cast(unsigned short, (__bf16)f);  // native cvt (RNE)
}
static __device__ __forceinline__ float bf2f(short s) {
  unsigned int u = ((unsigned int)(unsigned short)s) << 16;
  return __builtin_bit_cast(float, u);
}
static __device__ __forceinline__ float tanh_fast(float x) {
  float e = __builtin_amdgcn_exp2f(x * 2.88539008177792681f); // exp(2x)
  return 1.0f - 2.0f * __builtin_amdgcn_rcpf(e + 1.0f);
}
// base-2 logsumexp of 2 terms (finite-NEG safe)
static __device__ __forceinline__ float lse2_2(float a, float b) {
  float mx = fmaxf(a, b), mn = fminf(a, b);
  return mx + __builtin_amdgcn_logf(1.0f + __builtin_amdgcn_exp2f(mn - mx));
}

// ---------------- Kernel -1: prefill lp buffers with NEG -------------------
// Maskless alpha (r10): unwritten lattice slots + pad cols must read NEG.
__global__ __launch_bounds__(256) void fill_kernel(float* __restrict__ dst, int n4) {
  int i = blockIdx.x * 256 + threadIdx.x;
  if (i < n4) ((f32x4*)dst)[i] = (f32x4){NEGF, NEGF, NEGF, NEGF};
}

// ---------------- Kernel 0: weights fp32 -> bf16, MFMA-frag-linear pack -----
__global__ __launch_bounds__(256) void cvt_kernel(
    const float* __restrict__ Wf, const float* __restrict__ Wp,
    short* __restrict__ WfB, short* __restrict__ WpB) {
  int idx = blockIdx.x * 256 + threadIdx.x;
  const int nf = (512 * 640) / 4;   // 81920
  const int np = (V_DIM * NINNER) / 4;
  if (idx < nf) {
    float4 v = ((const float4*)Wf)[idx];
    int flat = idx * 4;
    int c = flat / 640;
    int kc = flat - c * 640;
    int part = (kc >= 320);
    int k0 = kc - (part ? 320 : 0);
    int dest = (part ? WF_PART : 0)
             + ((c >> 4) * 10 + (k0 >> 5)) * 512
             + (((k0 >> 3) & 3) * 16 + (c & 15)) * 8 + (k0 & 7);
    short4v o;
    o[0] = f2bf(v.x); o[1] = f2bf(v.y); o[2] = f2bf(v.z); o[3] = f2bf(v.w);
    *(short4v*)(WfB + dest) = o;
  } else if (idx < nf + np) {
    int j = idx - nf;
    float4 v = ((const float4*)Wp)[j];
    int flat = j * 4;
    int c = flat >> 9;
    int k0 = flat & 511;
    int dest = ((c >> 4) * 16 + (k0 >> 5)) * 512
             + (((k0 >> 3) & 3) * 16 + (c & 15)) * 8 + (k0 & 7);
    short4v o;
    o[0] = f2bf(v.x); o[1] = f2bf(v.y); o[2] = f2bf(v.z); o[3] = f2bf(v.w);
    *(short4v*)(WpB + dest) = o;
  }
}

// ---------------- Kernel 1: enc/dec projections (MFMA bf16) ----------------
// NOTE: no min-waves arg — min-waves>=4 on MFMA kernels splits the unified
// RF (Arch 64 / AGPR 64) and spills (r2/r3).
#define EP_BLOCKS 19
__global__ __launch_bounds__(256) void proj_kernel(
    const float* __restrict__ enc, const float* __restrict__ dec,
    const short* __restrict__ WfB, const float* __restrict__ bfv,
    short* __restrict__ epB, short* __restrict__ dpB) {
  const int half = blockIdx.x & 1;
  const int ob = blockIdx.x >> 1;
  const bool is_dp = (ob >= EP_BLOCKS);
  const int row0 = (is_dp ? ob - EP_BLOCKS : ob) * 64;
  const int nrows = is_dp ? DP_ROWS : EP_ROWS;
  const float* __restrict__ src = is_dp ? dec : enc;
  const short* __restrict__ bb = WfB + (is_dp ? WF_PART : 0);  // packed
  short* __restrict__ out = is_dp ? dpB : epB;

  __shared__ short As[64 * 320];  // 40 KB, XOR-swizzled
  const int tid = threadIdx.x;

  #pragma unroll
  for (int it = 0; it < 10; ++it) {
    int chunk = it * 256 + tid;        // 2560 chunks of 8 elems
    int m = chunk / 40;
    int c = chunk - m * 40;
    int r = row0 + m;
    short8 hv;
    #pragma unroll
    for (int j = 0; j < 8; ++j) hv[j] = 0;
    if (r < nrows) {
      const float* p = src + (size_t)r * 320 + c * 8;
      float4 a0 = *(const float4*)p;
      float4 a1 = *(const float4*)(p + 4);
      hv[0] = f2bf(a0.x); hv[1] = f2bf(a0.y); hv[2] = f2bf(a0.z); hv[3] = f2bf(a0.w);
      hv[4] = f2bf(a1.x); hv[5] = f2bf(a1.y); hv[6] = f2bf(a1.z); hv[7] = f2bf(a1.w);
    }
    int off = (m * 640 + c * 16) ^ ((m & 7) << 4);
    *(short8*)((char*)As + off) = hv;
  }
  __syncthreads();

  const int lane = tid & 63, wid = tid >> 6;
  const int lr = lane & 15, g = lane >> 4;

  int lin[4], xm[4];
  #pragma unroll
  for (int mf = 0; mf < 4; ++mf) {
    int row = mf * 16 + lr;
    lin[mf] = row * 640 + g * 16;
    xm[mf] = (row & 7) << 4;
  }

  const int n0 = half * 256 + wid * 64;
  const short* bptr[4];
  float bfc[4];
  #pragma unroll
  for (int nf2 = 0; nf2 < 4; ++nf2) {
    bptr[nf2] = bb + (n0 / 16 + nf2) * 5120 + lane * 8;   // frag-linear
    bfc[nf2] = is_dp ? bfv[n0 + nf2 * 16 + lr] : 0.f;
  }
  f32x4 acc[4][4];
  #pragma unroll
  for (int mf = 0; mf < 4; ++mf)
    #pragma unroll
    for (int nf2 = 0; nf2 < 4; ++nf2)
      acc[mf][nf2] = (f32x4){0.f, 0.f, 0.f, 0.f};

  #pragma unroll 2
  for (int kk = 0; kk < 10; ++kk) {
    bf16x8 av[4], bv[4];
    #pragma unroll
    for (int mf = 0; mf < 4; ++mf) {
      int off = (lin[mf] + (kk << 6)) ^ xm[mf];
      av[mf] = __builtin_bit_cast(bf16x8, *(const short8*)((const char*)As + off));
    }
    #pragma unroll
    for (int nf2 = 0; nf2 < 4; ++nf2)
      bv[nf2] = __builtin_bit_cast(bf16x8, *(const short8*)(bptr[nf2] + kk * 512));
    #pragma unroll
    for (int mf = 0; mf < 4; ++mf)
      #pragma unroll
      for (int nf2 = 0; nf2 < 4; ++nf2)
        acc[mf][nf2] = __builtin_amdgcn_mfma_f32_16x16x32_bf16(av[mf], bv[nf2], acc[mf][nf2], 0, 0, 0);
  }
  #pragma unroll
  for (int mf = 0; mf < 4; ++mf)
    #pragma unroll
    for (int nf2 = 0; nf2 < 4; ++nf2)
      #pragma unroll
      for (int rr = 0; rr < 4; ++rr) {
        int rowl = mf * 16 + g * 4 + rr;
        int grow = row0 + rowl;
        if (grow < nrows) {
          int col = n0 + nf2 * 16 + lr;
          out[(size_t)grow * NINNER + col] = f2bf(acc[mf][nf2][rr] + bfc[nf2]);
        }
      }
}

// ---------------- Kernel 2: fused joint + log-softmax slices ----------------
// r10: JROWS 48 (mf=3), LDS 49K+3K -> 3 blocks/CU (was 1-2 at 64K): fold/
// Phase-A VALU of one block overlaps MFMA of another (m114). Base-2 softmax,
// LOG2-domain outputs into PADDED diag layout (stride 82; lpb col base 1,
// lpe col base 2) for maskless alpha.
#define JROWS 48
__global__ __launch_bounds__(512) void joint_kernel(
    const short* __restrict__ epB, const short* __restrict__ dpB,
    const short* __restrict__ WpB, const float* __restrict__ bp,
    const int* __restrict__ tgt,
    float* __restrict__ lpb_p, float* __restrict__ lpe_p) {
  extern __shared__ char hbuf[];  // 48 * 512 * 2 = 49152 B
  __shared__ int ep_off[JROWS], dp_off[JROWS], bld_off[JROWS], eld_off[JROWS], tgt_s[JROWS];
  __shared__ float l0_s[JROWS], lt_s[JROWS];
  __shared__ float ws_s[8][JROWS];

  const int tid = threadIdx.x;
  const int row0 = blockIdx.x * JROWS;

  if (tid < JROWS) {
    int gr = row0 + tid;
    if (gr < NROWS) {
      int b = gr / (T_DIM * UP1);
      int rem = gr - b * (T_DIM * UP1);
      int t = rem / UP1;
      int u = rem - t * UP1;
      ep_off[tid] = (b * T_DIM + t) * NINNER;
      dp_off[tid] = (b * UP1 + u) * NINNER;
      bld_off[tid] = (b * NDIAG_B + (t + u)) * DSTRIDE + 1 + u;   // padded diag
      eld_off[tid] = (u < U_DIM) ? ((b * NDIAG_E + (t + u)) * DSTRIDE + 2 + u) : -1;
      tgt_s[tid] = (u < U_DIM) ? tgt[b * U_DIM + u] : 0;
    } else {
      ep_off[tid] = 0; dp_off[tid] = 0; bld_off[tid] = -1; eld_off[tid] = -1; tgt_s[tid] = 0;
    }
    l0_s[tid] = 0.f; lt_s[tid] = 0.f;
  }
  __syncthreads();

  // Phase A: h = tanh(ep+dp) into LDS (bf16 in, bf16 out, swizzled)
  #pragma unroll 2
  for (int it = 0; it < 6; ++it) {
    int chunk = it * 512 + tid;    // 3072 chunks of 8
    int m = chunk >> 6, c = chunk & 63;
    short8 hv;
    #pragma unroll
    for (int j = 0; j < 8; ++j) hv[j] = 0;
    if (bld_off[m] >= 0) {
      short8 ev = *(const short8*)(epB + ep_off[m] + c * 8);
      short8 dv = *(const short8*)(dpB + dp_off[m] + c * 8);
      #pragma unroll
      for (int j = 0; j < 8; ++j)
        hv[j] = f2bf(tanh_fast(bf2f(ev[j]) + bf2f(dv[j])));
    }
    int off = ((m << 10) + (c << 4)) ^ ((m & 7) << 4);
    *(short8*)(hbuf + off) = hv;
  }
  __syncthreads();

  const int lane = tid & 63, wid = tid >> 6;
  const int lr = lane & 15, g = lane >> 4;

  int lin[3], xm[3];
  #pragma unroll
  for (int mf = 0; mf < 3; ++mf) {
    int row = mf * 16 + lr;
    lin[mf] = (row << 10) + (g << 4);
    xm[mf] = (row & 7) << 4;
  }
  int tv[3][4];
  #pragma unroll
  for (int mf = 0; mf < 3; ++mf)
    #pragma unroll
    for (int rr = 0; rr < 4; ++rr)
      tv[mf][rr] = tgt_s[mf * 16 + g * 4 + rr];

  float rsum[3][4];
  #pragma unroll
  for (int mf = 0; mf < 3; ++mf)
    #pragma unroll
    for (int rr = 0; rr < 4; ++rr) rsum[mf][rr] = 0.f;

  #pragma unroll
  for (int sc = 0; sc < 2; ++sc) {
    const int n0 = wid * 128 + sc * 64;
    const short* bptr[4];
    float bpv[4];
    #pragma unroll
    for (int nf = 0; nf < 4; ++nf) {
      bptr[nf] = WpB + (n0 / 16 + nf) * 8192 + lane * 8;   // frag-linear
      bpv[nf] = bp[n0 + nf * 16 + lr] * LOG2E;             // scaled bias
    }
    f32x4 acc[3][4];
    #pragma unroll
    for (int mf = 0; mf < 3; ++mf)
      #pragma unroll
      for (int nf = 0; nf < 4; ++nf)
        acc[mf][nf] = (f32x4){0.f, 0.f, 0.f, 0.f};

    #pragma unroll 2
    for (int kk = 0; kk < 16; ++kk) {
      bf16x8 av[3], bv[4];
      #pragma unroll
      for (int mf = 0; mf < 3; ++mf) {
        int off = (lin[mf] + (kk << 6)) ^ xm[mf];
        av[mf] = __builtin_bit_cast(bf16x8, *(const short8*)(hbuf + off));
      }
      #pragma unroll
      for (int nf = 0; nf < 4; ++nf)
        bv[nf] = __builtin_bit_cast(bf16x8, *(const short8*)(bptr[nf] + kk * 512));
      __builtin_amdgcn_s_setprio(1);          // T5: favor MFMA burst
      #pragma unroll
      for (int mf = 0; mf < 3; ++mf)
        #pragma unroll
        for (int nf = 0; nf < 4; ++nf)
          acc[mf][nf] = __builtin_amdgcn_mfma_f32_16x16x32_bf16(av[mf], bv[nf], acc[mf][nf], 0, 0, 0);
      __builtin_amdgcn_s_setprio(0);
    }
    // fold: base-2 sum-of-exp2 over this 64-col subchunk (scaled logits)
    #pragma unroll
    for (int mf = 0; mf < 3; ++mf)
      #pragma unroll
      for (int rr = 0; rr < 4; ++rr) {
        float x0 = __builtin_fmaf(acc[mf][0][rr], LOG2E, bpv[0]);
        float x1 = __builtin_fmaf(acc[mf][1][rr], LOG2E, bpv[1]);
        float x2 = __builtin_fmaf(acc[mf][2][rr], LOG2E, bpv[2]);
        float x3 = __builtin_fmaf(acc[mf][3][rr], LOG2E, bpv[3]);
        int rowl = mf * 16 + g * 4 + rr;
        if (wid == 0 && sc == 0 && lr == 0) l0_s[rowl] = x0;  // v = 0 (scaled)
        int dtv = tv[mf][rr] - n0;
        if (dtv >= 0 && dtv < 64 && (dtv & 15) == lr) {
          int nfi = dtv >> 4;
          lt_s[rowl] = (nfi == 0) ? x0 : (nfi == 1) ? x1 : (nfi == 2) ? x2 : x3;
        }
        rsum[mf][rr] += __builtin_amdgcn_exp2f(x0) + __builtin_amdgcn_exp2f(x1)
                      + __builtin_amdgcn_exp2f(x2) + __builtin_amdgcn_exp2f(x3);
      }
  }
  // add-butterfly across the 16 lanes of each group
  #pragma unroll
  for (int mf = 0; mf < 3; ++mf)
    #pragma unroll
    for (int rr = 0; rr < 4; ++rr) {
      float s_ = rsum[mf][rr];
      #pragma unroll
      for (int o = 1; o < 16; o <<= 1) s_ += __shfl_xor(s_, o);
      if (lr == 0) ws_s[wid][mf * 16 + g * 4 + rr] = s_;
    }
  __syncthreads();
  if (tid < JROWS) {
    int bo = bld_off[tid];
    if (bo >= 0) {
      float S = 0.f;
      #pragma unroll
      for (int w = 0; w < 8; ++w) S += ws_s[w][tid];
      float lse2v = __builtin_amdgcn_logf(S);   // log2
      lpb_p[bo] = l0_s[tid] - lse2v;            // LOG2 DOMAIN
      int eo = eld_off[tid];
      if (eo >= 0) lpe_p[eo] = lt_s[tid] - lse2v;
    }
  }
}

// ---------------- Kernel 3: alpha DP, maskless reg-resident (r10) -----------
// r9 lesson: ~24 mask cndmasks/round dominate issue at 1 wave/SIMD. r10: all
// t/u validity masks replaced by NEG-prefilled padded layout — unwritten
// lattice slots and the 1/2-col left pads read -1e30; invalid paths die via
// +NEG and exp2(-huge)=0 EXACTLY; fmax(na,NEG) clamp prevents -inf/NaN drift.
// Ghost cells (t>T-1) never feed valid cells (valid cell's predecessors are
// valid). Math otherwise identical to validated r8/r9. LOG2 domain.
#define ACH 8
#define NCH 48   /* s1 reaches 383 >= dstar max 379 */
__global__ __launch_bounds__(256) void alpha_kernel(
    const float* __restrict__ lpb_p, const float* __restrict__ lpe_p,
    const int* __restrict__ ilen, const int* __restrict__ ulen_,
    float* __restrict__ out) {
  __shared__ float lls[B_DIM];
  const int tid = threadIdx.x;
  const int b = tid >> 6;
  const int lane = tid & 63;
  const float NEG = NEGF;
  const int tl = ilen[b], ul = ulen_[b];
  const int dstar = tl - 1 + ul;          // final-cell diagonal

  const int u0 = lane;           // slot 0: u = 0..63
  const int u1 = 64 + lane;      // slot 1: u = 64..80 (lane < 17)
  const bool act1 = (u1 <= 80);
  const int uc1 = act1 ? u1 : 80;

  const float* pbb = lpb_p + (size_t)b * (NDIAG_B * DSTRIDE);
  const float* peb = lpe_p + (size_t)b * (NDIAG_E * DSTRIDE);

  // register buffers: per slot {blank@u, blank@u-1, emit@u-1, emit@u-2}
  float Ab0r[ACH], Ab0m[ACH], Ae0r[ACH], Ae0m[ACH];
  float Ab1r[ACH], Ab1m[ACH], Ae1r[ACH], Ae1m[ACH];
  float Bb0r[ACH], Bb0m[ACH], Be0r[ACH], Be0m[ACH];
  float Bb1r[ACH], Bb1m[ACH], Be1r[ACH], Be1m[ACH];

  #define ALOAD(P, c)                                                        \
    {                                                                        \
      _Pragma("unroll")                                                      \
      for (int j = 0; j < ACH; ++j) {                                        \
        int dd = (c) * ACH + j;                                              \
        int ddb = dd < NDIAG_B ? dd : NDIAG_B - 1;                           \
        int dde = dd < NDIAG_E ? dd : NDIAG_E - 1;                           \
        const float* rb_ = pbb + ddb * DSTRIDE + 1;                          \
        const float* re_ = peb + dde * DSTRIDE + 2;                          \
        P##b0r[j] = rb_[u0];                                                 \
        P##b0m[j] = rb_[u0 - 1];                                             \
        P##e0r[j] = re_[u0 - 1];                                             \
        P##e0m[j] = re_[u0 - 2];                                             \
        P##b1r[j] = rb_[uc1];                                                \
        P##b1m[j] = rb_[uc1 - 1];                                            \
        P##e1r[j] = re_[uc1 - 1];                                            \
        P##e1m[j] = re_[uc1 - 2];                                            \
      }                                                                      \
    }

  #define ACOMP(P, c)                                                        \
    {                                                                        \
      _Pragma("unroll")                                                      \
      for (int q = 0; q < ACH / 2; ++q) {                                    \
        const int j = 2 * q;                                                 \
        const int s1 = (c) * ACH + j + 1;                                    \
        float s0m1 = __shfl(pa0, (lane + 63) & 63);                          \
        float s0m2 = __shfl(pa0, (lane + 62) & 63);                          \
        float s1m1 = __shfl(pa1, (lane + 63) & 63);                          \
        float s1m2 = __shfl(pa1, (lane + 62) & 63);                          \
        float na0, na1;                                                      \
        { /* slot 0 — maskless: pads/unwritten slots are NEG */              \
          float b1 = P##b0r[j], b2 = P##b0r[j + 1];                          \
          float e1 = P##e0r[j], e2 = P##e0r[j + 1];                          \
          float b1m = P##b0m[j], e1m = P##e0m[j];                            \
          float T1 = b1 + b2;                                                \
          float T2 = lse2_2(e1 + b2, b1m + e2);                              \
          float T3 = e1m + e2;                                               \
          float p0 = pa0 + T1;                                               \
          float p1 = s0m1 + T2;                                              \
          float p2 = s0m2 + T3;                                              \
          float mx = fmaxf(fmaxf(p0, p1), p2);                               \
          float ss = __builtin_amdgcn_exp2f(p0 - mx)                         \
                   + __builtin_amdgcn_exp2f(p1 - mx)                         \
                   + __builtin_amdgcn_exp2f(p2 - mx);                        \
          na0 = fmaxf(mx + __builtin_amdgcn_logf(ss), NEG);                  \
        }                                                                    \
        { /* slot 1 */                                                       \
          float b1 = P##b1r[j], b2 = P##b1r[j + 1];                          \
          float e1 = P##e1r[j], e2 = P##e1r[j + 1];                          \
          float b1m = P##b1m[j], e1m = P##e1m[j];                            \
          float pm1 = (lane == 0) ? s0m1 : s1m1;                             \
          float pm2 = (lane <= 1) ? s0m2 : s1m2;                             \
          float T1 = b1 + b2;                                                \
          float T2 = lse2_2(e1 + b2, b1m + e2);                              \
          float T3 = e1m + e2;                                               \
          float p0 = pa1 + T1;                                               \
          float p1 = pm1 + T2;                                               \
          float p2 = pm2 + T3;                                               \
          float mx = fmaxf(fmaxf(p0, p1), p2);                               \
          float ss = __builtin_amdgcn_exp2f(p0 - mx)                         \
                   + __builtin_amdgcn_exp2f(p1 - mx)                         \
                   + __builtin_amdgcn_exp2f(p2 - mx);                        \
          na1 = fmaxf(mx + __builtin_amdgcn_logf(ss), NEG);                  \
        }                                                                    \
        if (s1 == dstar) { /* odd-diagonal final capture (scalar branch) */  \
          float vo0 = lse2_2(pa0 + P##b0r[j], s0m1 + P##e0r[j]);             \
          if (u0 == ul) fin = vo0;                                           \
          float pm1c = (lane == 0) ? s0m1 : s1m1;                            \
          float vo1 = lse2_2(pa1 + P##b1r[j], pm1c + P##e1r[j]);             \
          if (act1 && u1 == ul) fin = vo1;                                   \
        }                                                                    \
        pa0 = na0; pa1 = na1;                                                \
        if (s1 + 1 == dstar) { /* even-diagonal final capture */             \
          if (u0 == ul) fin = pa0;                                           \
          if (act1 && u1 == ul) fin = pa1;                                   \
        }                                                                    \
      }                                                                      \
    }

  float pa0 = (u0 == 0) ? 0.f : NEG;  // alpha on diag 0 (log2 domain)
  float pa1 = NEG;
  float fin = NEG;
  if (dstar == 0 && u0 == ul) fin = pa0;   // tl=1, ul=0 corner

  ALOAD(A, 0);
  for (int p = 0; p < NCH / 2; ++p) {
    const int cA = 2 * p, cB = 2 * p + 1;
    ALOAD(B, cB);        // issue next chunk's loads (covered by ACOMP(A))
    ACOMP(A, cA);
    ALOAD(A, cA + 2);    // final iteration clamps to last rows — harmless
    ACOMP(B, cB);
  }

  #pragma unroll
  for (int o = 32; o; o >>= 1) fin = fmaxf(fin, __shfl_xor(fin, o));
  if (lane == 0) {
    float last = pbb[(size_t)dstar * DSTRIDE + 1 + ul];   // log2 domain
    lls[b] = fin + last;
  }
  __syncthreads();
  if (tid == 0)
    out[0] = -(lls[0] + lls[1] + lls[2] + lls[3]) * (LN2 * 0.25f);
}

// ---------------- launcher ----------------
extern "C" void kernel_launch(void* const* d_in, const int* in_sizes, int n_in,
                              void* d_out, int out_size, void* d_ws, size_t ws_size,
                              hipStream_t stream) {
  const float* enc = (const float*)d_in[0];
  const float* dec = (const float*)d_in[1];
  const float* Wf  = (const float*)d_in[2];
  const float* bfv = (const float*)d_in[3];
  const float* Wp  = (const float*)d_in[4];
  const float* bp  = (const float*)d_in[5];
  const int* targets = (const int*)d_in[6];
  const int* ilen    = (const int*)d_in[7];
  const int* ulen    = (const int*)d_in[8];
  float* out = (float*)d_out;
  char* ws = (char*)d_ws;

  short* WfB   = (short*)(ws + 0);          //   655360 B (packed)
  short* WpB   = (short*)(ws + 655360);     //  1048576 B (packed) -> 1703936
  short* epB   = (short*)(ws + 1703936);    //  1228800 B (bf16)   -> 2932736
  short* dpB   = (short*)(ws + 2932736);    //   331776 B (bf16)   -> 3264512
  float* lpb_p = (float*)(ws + 3264512);    //   498560 B (4*380*82) -> 3763072
  float* lpe_p = (float*)(ws + 3763072);    //   497248 B (4*379*82) -> 4260320
  const int FILL_N4 = (4 * NDIAG_B * DSTRIDE + 4 * NDIAG_E * DSTRIDE) / 4; // 62238

  fill_kernel<<<(FILL_N4 + 255) / 256, 256, 0, stream>>>(lpb_p, FILL_N4);
  cvt_kernel<<<832, 256, 0, stream>>>(Wf, Wp, WfB, WpB);
  proj_kernel<<<50, 256, 0, stream>>>(enc, dec, WfB, bfv, epB, dpB);
  joint_kernel<<<NROWS / JROWS, 512, 49152, stream>>>(epB, dpB, WpB, bp, targets, lpb_p, lpe_p);
  alpha_kernel<<<1, 256, 0, stream>>>(lpb_p, lpe_p, ilen, ulen, out);
}

// Round 11
// 218.240 us; speedup vs baseline: 1.0745x; 1.0745x over previous
//
#include <hip/hip_runtime.h>

#define B_DIM 4
#define T_DIM 300
#define U_DIM 80
#define UP1   81
#define V_DIM 1024
#define NINNER 512
#define NROWS (B_DIM * T_DIM * UP1)   /* 97200 */
#define EP_ROWS (B_DIM * T_DIM)       /* 1200 */
#define DP_ROWS (B_DIM * UP1)         /* 324 */
#define NDIAG_B 380                    /* t+u diagonals for lpb */
#define NDIAG_E 379                    /* t+u diagonals for lpe */
#define DSTRIDE 82                     /* padded diag-row stride (floats) */
#define WF_PART 163840                 /* 512 cols x 320 k, per half of Wf */
#define LOG2E 1.44269504088896341f
#define LN2   0.69314718055994531f
#define NEGF  -1e30f

typedef float f32x4 __attribute__((ext_vector_type(4)));
typedef short short8 __attribute__((ext_vector_type(8)));
typedef short short4v __attribute__((ext_vector_type(4)));
typedef __bf16 bf16x8 __attribute__((ext_vector_type(8)));

static __device__ __forceinline__ short f2bf(float f) {
  return (short)__builtin_bit_cast(unsigned short, (__bf16)f);  // native cvt (RNE)
}
static __device__ __forceinline__ float bf2f(short s) {
  unsigned int u = ((unsigned int)(unsigned short)s) << 16;
  return __builtin_bit_cast(float, u);
}
static __device__ __forceinline__ float tanh_fast(float x) {
  float e = __builtin_amdgcn_exp2f(x * 2.88539008177792681f); // exp(2x)
  return 1.0f - 2.0f * __builtin_amdgcn_rcpf(e + 1.0f);
}
// base-2 logsumexp of 2 terms (finite-NEG safe)
static __device__ __forceinline__ float lse2_2(float a, float b) {
  float mx = fmaxf(a, b), mn = fminf(a, b);
  return mx + __builtin_amdgcn_logf(1.0f + __builtin_amdgcn_exp2f(mn - mx));
}
// DPP wave_ror:1 — dst[i] = src[(i+63)&63]; VALU pipe, no LDS unit (r11).
static __device__ __forceinline__ float ror1f(float x) {
  int r = __builtin_amdgcn_update_dpp(0, __builtin_bit_cast(int, x),
                                      0x13C /*WAVE_ROR1*/, 0xF, 0xF, true);
  return __builtin_bit_cast(float, r);
}
static __device__ __forceinline__ float readlanef(float x, int l) {
  return __builtin_bit_cast(float,
      __builtin_amdgcn_readlane(__builtin_bit_cast(int, x), l));
}

// ---------------- Kernel -1: prefill lp buffers with NEG -------------------
__global__ __launch_bounds__(256) void fill_kernel(float* __restrict__ dst, int n4) {
  int i = blockIdx.x * 256 + threadIdx.x;
  if (i < n4) ((f32x4*)dst)[i] = (f32x4){NEGF, NEGF, NEGF, NEGF};
}

// ---------------- Kernel 0: weights fp32 -> bf16, MFMA-frag-linear pack -----
__global__ __launch_bounds__(256) void cvt_kernel(
    const float* __restrict__ Wf, const float* __restrict__ Wp,
    short* __restrict__ WfB, short* __restrict__ WpB) {
  int idx = blockIdx.x * 256 + threadIdx.x;
  const int nf = (512 * 640) / 4;   // 81920
  const int np = (V_DIM * NINNER) / 4;
  if (idx < nf) {
    float4 v = ((const float4*)Wf)[idx];
    int flat = idx * 4;
    int c = flat / 640;
    int kc = flat - c * 640;
    int part = (kc >= 320);
    int k0 = kc - (part ? 320 : 0);
    int dest = (part ? WF_PART : 0)
             + ((c >> 4) * 10 + (k0 >> 5)) * 512
             + (((k0 >> 3) & 3) * 16 + (c & 15)) * 8 + (k0 & 7);
    short4v o;
    o[0] = f2bf(v.x); o[1] = f2bf(v.y); o[2] = f2bf(v.z); o[3] = f2bf(v.w);
    *(short4v*)(WfB + dest) = o;
  } else if (idx < nf + np) {
    int j = idx - nf;
    float4 v = ((const float4*)Wp)[j];
    int flat = j * 4;
    int c = flat >> 9;
    int k0 = flat & 511;
    int dest = ((c >> 4) * 16 + (k0 >> 5)) * 512
             + (((k0 >> 3) & 3) * 16 + (c & 15)) * 8 + (k0 & 7);
    short4v o;
    o[0] = f2bf(v.x); o[1] = f2bf(v.y); o[2] = f2bf(v.z); o[3] = f2bf(v.w);
    *(short4v*)(WpB + dest) = o;
  }
}

// ---------------- Kernel 1: enc/dec projections (MFMA bf16) ----------------
// NOTE: no min-waves arg — min-waves>=4 on MFMA kernels splits the unified
// RF (Arch 64 / AGPR 64) and spills (r2/r3).
#define EP_BLOCKS 19
__global__ __launch_bounds__(256) void proj_kernel(
    const float* __restrict__ enc, const float* __restrict__ dec,
    const short* __restrict__ WfB, const float* __restrict__ bfv,
    short* __restrict__ epB, short* __restrict__ dpB) {
  const int half = blockIdx.x & 1;
  const int ob = blockIdx.x >> 1;
  const bool is_dp = (ob >= EP_BLOCKS);
  const int row0 = (is_dp ? ob - EP_BLOCKS : ob) * 64;
  const int nrows = is_dp ? DP_ROWS : EP_ROWS;
  const float* __restrict__ src = is_dp ? dec : enc;
  const short* __restrict__ bb = WfB + (is_dp ? WF_PART : 0);  // packed
  short* __restrict__ out = is_dp ? dpB : epB;

  __shared__ short As[64 * 320];  // 40 KB, XOR-swizzled
  const int tid = threadIdx.x;

  #pragma unroll
  for (int it = 0; it < 10; ++it) {
    int chunk = it * 256 + tid;        // 2560 chunks of 8 elems
    int m = chunk / 40;
    int c = chunk - m * 40;
    int r = row0 + m;
    short8 hv;
    #pragma unroll
    for (int j = 0; j < 8; ++j) hv[j] = 0;
    if (r < nrows) {
      const float* p = src + (size_t)r * 320 + c * 8;
      float4 a0 = *(const float4*)p;
      float4 a1 = *(const float4*)(p + 4);
      hv[0] = f2bf(a0.x); hv[1] = f2bf(a0.y); hv[2] = f2bf(a0.z); hv[3] = f2bf(a0.w);
      hv[4] = f2bf(a1.x); hv[5] = f2bf(a1.y); hv[6] = f2bf(a1.z); hv[7] = f2bf(a1.w);
    }
    int off = (m * 640 + c * 16) ^ ((m & 7) << 4);
    *(short8*)((char*)As + off) = hv;
  }
  __syncthreads();

  const int lane = tid & 63, wid = tid >> 6;
  const int lr = lane & 15, g = lane >> 4;

  int lin[4], xm[4];
  #pragma unroll
  for (int mf = 0; mf < 4; ++mf) {
    int row = mf * 16 + lr;
    lin[mf] = row * 640 + g * 16;
    xm[mf] = (row & 7) << 4;
  }

  const int n0 = half * 256 + wid * 64;
  const short* bptr[4];
  float bfc[4];
  #pragma unroll
  for (int nf2 = 0; nf2 < 4; ++nf2) {
    bptr[nf2] = bb + (n0 / 16 + nf2) * 5120 + lane * 8;   // frag-linear
    bfc[nf2] = is_dp ? bfv[n0 + nf2 * 16 + lr] : 0.f;
  }
  f32x4 acc[4][4];
  #pragma unroll
  for (int mf = 0; mf < 4; ++mf)
    #pragma unroll
    for (int nf2 = 0; nf2 < 4; ++nf2)
      acc[mf][nf2] = (f32x4){0.f, 0.f, 0.f, 0.f};

  #pragma unroll 2
  for (int kk = 0; kk < 10; ++kk) {
    bf16x8 av[4], bv[4];
    #pragma unroll
    for (int mf = 0; mf < 4; ++mf) {
      int off = (lin[mf] + (kk << 6)) ^ xm[mf];
      av[mf] = __builtin_bit_cast(bf16x8, *(const short8*)((const char*)As + off));
    }
    #pragma unroll
    for (int nf2 = 0; nf2 < 4; ++nf2)
      bv[nf2] = __builtin_bit_cast(bf16x8, *(const short8*)(bptr[nf2] + kk * 512));
    #pragma unroll
    for (int mf = 0; mf < 4; ++mf)
      #pragma unroll
      for (int nf2 = 0; nf2 < 4; ++nf2)
        acc[mf][nf2] = __builtin_amdgcn_mfma_f32_16x16x32_bf16(av[mf], bv[nf2], acc[mf][nf2], 0, 0, 0);
  }
  #pragma unroll
  for (int mf = 0; mf < 4; ++mf)
    #pragma unroll
    for (int nf2 = 0; nf2 < 4; ++nf2)
      #pragma unroll
      for (int rr = 0; rr < 4; ++rr) {
        int rowl = mf * 16 + g * 4 + rr;
        int grow = row0 + rowl;
        if (grow < nrows) {
          int col = n0 + nf2 * 16 + lr;
          out[(size_t)grow * NINNER + col] = f2bf(acc[mf][nf2][rr] + bfc[nf2]);
        }
      }
}

// ---------------- Kernel 2: fused joint + log-softmax slices ----------------
// r11: reverted to r9 champion (JROWS 64, mf=4, 64KB LDS — 140us; r10's
// JROWS48/mf3 regressed: +33% B-traffic, occupancy did NOT rise). Base-2
// softmax, LOG2-domain outputs into PADDED diag layout (stride 82; lpb col
// base 1, lpe col base 2) for maskless alpha. T5 setprio around MFMA bursts.
#define JROWS 64
__global__ __launch_bounds__(512) void joint_kernel(
    const short* __restrict__ epB, const short* __restrict__ dpB,
    const short* __restrict__ WpB, const float* __restrict__ bp,
    const int* __restrict__ tgt,
    float* __restrict__ lpb_p, float* __restrict__ lpe_p) {
  extern __shared__ char hbuf[];  // 64 * 512 * 2 = 65536 B
  __shared__ int ep_off[JROWS], dp_off[JROWS], bld_off[JROWS], eld_off[JROWS], tgt_s[JROWS];
  __shared__ float l0_s[JROWS], lt_s[JROWS];
  __shared__ float ws_s[8][JROWS];

  const int tid = threadIdx.x;
  const int row0 = blockIdx.x * JROWS;

  if (tid < JROWS) {
    int gr = row0 + tid;
    if (gr < NROWS) {
      int b = gr / (T_DIM * UP1);
      int rem = gr - b * (T_DIM * UP1);
      int t = rem / UP1;
      int u = rem - t * UP1;
      ep_off[tid] = (b * T_DIM + t) * NINNER;
      dp_off[tid] = (b * UP1 + u) * NINNER;
      bld_off[tid] = (b * NDIAG_B + (t + u)) * DSTRIDE + 1 + u;   // padded diag
      eld_off[tid] = (u < U_DIM) ? ((b * NDIAG_E + (t + u)) * DSTRIDE + 2 + u) : -1;
      tgt_s[tid] = (u < U_DIM) ? tgt[b * U_DIM + u] : 0;
    } else {
      ep_off[tid] = 0; dp_off[tid] = 0; bld_off[tid] = -1; eld_off[tid] = -1; tgt_s[tid] = 0;
    }
    l0_s[tid] = 0.f; lt_s[tid] = 0.f;
  }
  __syncthreads();

  // Phase A: h = tanh(ep+dp) into LDS (bf16 in, bf16 out, swizzled)
  #pragma unroll 2
  for (int it = 0; it < 8; ++it) {
    int chunk = it * 512 + tid;    // 4096 chunks of 8
    int m = chunk >> 6, c = chunk & 63;
    short8 hv;
    #pragma unroll
    for (int j = 0; j < 8; ++j) hv[j] = 0;
    if (bld_off[m] >= 0) {
      short8 ev = *(const short8*)(epB + ep_off[m] + c * 8);
      short8 dv = *(const short8*)(dpB + dp_off[m] + c * 8);
      #pragma unroll
      for (int j = 0; j < 8; ++j)
        hv[j] = f2bf(tanh_fast(bf2f(ev[j]) + bf2f(dv[j])));
    }
    int off = ((m << 10) + (c << 4)) ^ ((m & 7) << 4);
    *(short8*)(hbuf + off) = hv;
  }
  __syncthreads();

  const int lane = tid & 63, wid = tid >> 6;
  const int lr = lane & 15, g = lane >> 4;

  int lin[4], xm[4];
  #pragma unroll
  for (int mf = 0; mf < 4; ++mf) {
    int row = mf * 16 + lr;
    lin[mf] = (row << 10) + (g << 4);
    xm[mf] = (row & 7) << 4;
  }
  int tv[4][4];
  #pragma unroll
  for (int mf = 0; mf < 4; ++mf)
    #pragma unroll
    for (int rr = 0; rr < 4; ++rr)
      tv[mf][rr] = tgt_s[mf * 16 + g * 4 + rr];

  float rsum[4][4];
  #pragma unroll
  for (int mf = 0; mf < 4; ++mf)
    #pragma unroll
    for (int rr = 0; rr < 4; ++rr) rsum[mf][rr] = 0.f;

  #pragma unroll
  for (int sc = 0; sc < 2; ++sc) {
    const int n0 = wid * 128 + sc * 64;
    const short* bptr[4];
    float bpv[4];
    #pragma unroll
    for (int nf = 0; nf < 4; ++nf) {
      bptr[nf] = WpB + (n0 / 16 + nf) * 8192 + lane * 8;   // frag-linear
      bpv[nf] = bp[n0 + nf * 16 + lr] * LOG2E;             // scaled bias
    }
    f32x4 acc[4][4];
    #pragma unroll
    for (int mf = 0; mf < 4; ++mf)
      #pragma unroll
      for (int nf = 0; nf < 4; ++nf)
        acc[mf][nf] = (f32x4){0.f, 0.f, 0.f, 0.f};

    #pragma unroll 2
    for (int kk = 0; kk < 16; ++kk) {
      bf16x8 av[4], bv[4];
      #pragma unroll
      for (int mf = 0; mf < 4; ++mf) {
        int off = (lin[mf] + (kk << 6)) ^ xm[mf];
        av[mf] = __builtin_bit_cast(bf16x8, *(const short8*)(hbuf + off));
      }
      #pragma unroll
      for (int nf = 0; nf < 4; ++nf)
        bv[nf] = __builtin_bit_cast(bf16x8, *(const short8*)(bptr[nf] + kk * 512));
      __builtin_amdgcn_s_setprio(1);          // T5: favor MFMA burst
      #pragma unroll
      for (int mf = 0; mf < 4; ++mf)
        #pragma unroll
        for (int nf = 0; nf < 4; ++nf)
          acc[mf][nf] = __builtin_amdgcn_mfma_f32_16x16x32_bf16(av[mf], bv[nf], acc[mf][nf], 0, 0, 0);
      __builtin_amdgcn_s_setprio(0);
    }
    // fold: base-2 sum-of-exp2 over this 64-col subchunk (scaled logits)
    #pragma unroll
    for (int mf = 0; mf < 4; ++mf)
      #pragma unroll
      for (int rr = 0; rr < 4; ++rr) {
        float x0 = __builtin_fmaf(acc[mf][0][rr], LOG2E, bpv[0]);
        float x1 = __builtin_fmaf(acc[mf][1][rr], LOG2E, bpv[1]);
        float x2 = __builtin_fmaf(acc[mf][2][rr], LOG2E, bpv[2]);
        float x3 = __builtin_fmaf(acc[mf][3][rr], LOG2E, bpv[3]);
        int rowl = mf * 16 + g * 4 + rr;
        if (wid == 0 && sc == 0 && lr == 0) l0_s[rowl] = x0;  // v = 0 (scaled)
        int dtv = tv[mf][rr] - n0;
        if (dtv >= 0 && dtv < 64 && (dtv & 15) == lr) {
          int nfi = dtv >> 4;
          lt_s[rowl] = (nfi == 0) ? x0 : (nfi == 1) ? x1 : (nfi == 2) ? x2 : x3;
        }
        rsum[mf][rr] += __builtin_amdgcn_exp2f(x0) + __builtin_amdgcn_exp2f(x1)
                      + __builtin_amdgcn_exp2f(x2) + __builtin_amdgcn_exp2f(x3);
      }
  }
  // add-butterfly across the 16 lanes of each group
  #pragma unroll
  for (int mf = 0; mf < 4; ++mf)
    #pragma unroll
    for (int rr = 0; rr < 4; ++rr) {
      float s_ = rsum[mf][rr];
      #pragma unroll
      for (int o = 1; o < 16; o <<= 1) s_ += __shfl_xor(s_, o);
      if (lr == 0) ws_s[wid][mf * 16 + g * 4 + rr] = s_;
    }
  __syncthreads();
  if (tid < JROWS) {
    int bo = bld_off[tid];
    if (bo >= 0) {
      float S = 0.f;
      #pragma unroll
      for (int w = 0; w < 8; ++w) S += ws_s[w][tid];
      float lse2v = __builtin_amdgcn_logf(S);   // log2
      lpb_p[bo] = l0_s[tid] - lse2v;            // LOG2 DOMAIN
      int eo = eld_off[tid];
      if (eo >= 0) lpe_p[eo] = lt_s[tid] - lse2v;
    }
  }
}

// ---------------- Kernel 3: alpha DP, maskless + DPP neighbors (r11) --------
// r8 null (chain-halving) + r10 near-null (mask removal) + r9 win (LDS-read
// removal) => model: the CU's shared LDS pipe is saturated by 16 ds_bpermute
// per round (4 waves x 4 __shfl). r11: neighbor alphas via DPP wave_ror:1
// (VALU pipe, ~4cy, no LDS unit). Slot-0 wrap lanes (0/1) are dead via NEG
// pads (r10-validated); slot-1 lanes 0/1 patched with v_readlane of pa0.
#define ACH 8
#define NCH 48   /* s1 reaches 383 >= dstar max 379 */
__global__ __launch_bounds__(256) void alpha_kernel(
    const float* __restrict__ lpb_p, const float* __restrict__ lpe_p,
    const int* __restrict__ ilen, const int* __restrict__ ulen_,
    float* __restrict__ out) {
  __shared__ float lls[B_DIM];
  const int tid = threadIdx.x;
  const int b = tid >> 6;
  const int lane = tid & 63;
  const float NEG = NEGF;
  const int tl = ilen[b], ul = ulen_[b];
  const int dstar = tl - 1 + ul;          // final-cell diagonal

  const int u0 = lane;           // slot 0: u = 0..63
  const int u1 = 64 + lane;      // slot 1: u = 64..80 (lane < 17)
  const bool act1 = (u1 <= 80);
  const int uc1 = act1 ? u1 : 80;

  const float* pbb = lpb_p + (size_t)b * (NDIAG_B * DSTRIDE);
  const float* peb = lpe_p + (size_t)b * (NDIAG_E * DSTRIDE);

  // register buffers: per slot {blank@u, blank@u-1, emit@u-1, emit@u-2}
  float Ab0r[ACH], Ab0m[ACH], Ae0r[ACH], Ae0m[ACH];
  float Ab1r[ACH], Ab1m[ACH], Ae1r[ACH], Ae1m[ACH];
  float Bb0r[ACH], Bb0m[ACH], Be0r[ACH], Be0m[ACH];
  float Bb1r[ACH], Bb1m[ACH], Be1r[ACH], Be1m[ACH];

  #define ALOAD(P, c)                                                        \
    {                                                                        \
      _Pragma("unroll")                                                      \
      for (int j = 0; j < ACH; ++j) {                                        \
        int dd = (c) * ACH + j;                                              \
        int ddb = dd < NDIAG_B ? dd : NDIAG_B - 1;                           \
        int dde = dd < NDIAG_E ? dd : NDIAG_E - 1;                           \
        const float* rb_ = pbb + ddb * DSTRIDE + 1;                          \
        const float* re_ = peb + dde * DSTRIDE + 2;                          \
        P##b0r[j] = rb_[u0];                                                 \
        P##b0m[j] = rb_[u0 - 1];                                             \
        P##e0r[j] = re_[u0 - 1];                                             \
        P##e0m[j] = re_[u0 - 2];                                             \
        P##b1r[j] = rb_[uc1];                                                \
        P##b1m[j] = rb_[uc1 - 1];                                            \
        P##e1r[j] = re_[uc1 - 1];                                            \
        P##e1m[j] = re_[uc1 - 2];                                            \
      }                                                                      \
    }

  #define ACOMP(P, c)                                                        \
    {                                                                        \
      _Pragma("unroll")                                                      \
      for (int q = 0; q < ACH / 2; ++q) {                                    \
        const int j = 2 * q;                                                 \
        const int s1 = (c) * ACH + j + 1;                                    \
        /* neighbor alphas via DPP (VALU), not ds_bpermute (LDS pipe) */     \
        float a63 = readlanef(pa0, 63), a62 = readlanef(pa0, 62);            \
        float s0m1 = ror1f(pa0);                                             \
        float s0m2 = ror1f(s0m1);                                            \
        float s1m1r = ror1f(pa1);                                            \
        float s1m2r = ror1f(s1m1r);                                          \
        float s1m1 = (lane == 0) ? a63 : s1m1r;                              \
        float s1m2 = (lane == 0) ? a62 : ((lane == 1) ? a63 : s1m2r);        \
        float na0, na1;                                                      \
        { /* slot 0 — maskless: pads/unwritten slots are NEG */              \
          float b1 = P##b0r[j], b2 = P##b0r[j + 1];                          \
          float e1 = P##e0r[j], e2 = P##e0r[j + 1];                          \
          float b1m = P##b0m[j], e1m = P##e0m[j];                            \
          float T1 = b1 + b2;                                                \
          float T2 = lse2_2(e1 + b2, b1m + e2);                              \
          float T3 = e1m + e2;                                               \
          float p0 = pa0 + T1;                                               \
          float p1 = s0m1 + T2;                                              \
          float p2 = s0m2 + T3;                                              \
          float mx = fmaxf(fmaxf(p0, p1), p2);                               \
          float ss = __builtin_amdgcn_exp2f(p0 - mx)                         \
                   + __builtin_amdgcn_exp2f(p1 - mx)                         \
                   + __builtin_amdgcn_exp2f(p2 - mx);                        \
          na0 = fmaxf(mx + __builtin_amdgcn_logf(ss), NEG);                  \
        }                                                                    \
        { /* slot 1 */                                                       \
          float b1 = P##b1r[j], b2 = P##b1r[j + 1];                          \
          float e1 = P##e1r[j], e2 = P##e1r[j + 1];                          \
          float b1m = P##b1m[j], e1m = P##e1m[j];                            \
          float T1 = b1 + b2;                                                \
          float T2 = lse2_2(e1 + b2, b1m + e2);                              \
          float T3 = e1m + e2;                                               \
          float p0 = pa1 + T1;                                               \
          float p1 = s1m1 + T2;                                              \
          float p2 = s1m2 + T3;                                              \
          float mx = fmaxf(fmaxf(p0, p1), p2);                               \
          float ss = __builtin_amdgcn_exp2f(p0 - mx)                         \
                   + __builtin_amdgcn_exp2f(p1 - mx)                         \
                   + __builtin_amdgcn_exp2f(p2 - mx);                        \
          na1 = fmaxf(mx + __builtin_amdgcn_logf(ss), NEG);                  \
        }                                                                    \
        if (s1 == dstar) { /* odd-diagonal final capture (scalar branch) */  \
          float vo0 = lse2_2(pa0 + P##b0r[j], s0m1 + P##e0r[j]);             \
          if (u0 == ul) fin = vo0;                                           \
          float vo1 = lse2_2(pa1 + P##b1r[j], s1m1 + P##e1r[j]);             \
          if (act1 && u1 == ul) fin = vo1;                                   \
        }                                                                    \
        pa0 = na0; pa1 = na1;                                                \
        if (s1 + 1 == dstar) { /* even-diagonal final capture */             \
          if (u0 == ul) fin = pa0;                                           \
          if (act1 && u1 == ul) fin = pa1;                                   \
        }                                                                    \
      }                                                                      \
    }

  float pa0 = (u0 == 0) ? 0.f : NEG;  // alpha on diag 0 (log2 domain)
  float pa1 = NEG;
  float fin = NEG;
  if (dstar == 0 && u0 == ul) fin = pa0;   // tl=1, ul=0 corner

  ALOAD(A, 0);
  for (int p = 0; p < NCH / 2; ++p) {
    const int cA = 2 * p, cB = 2 * p + 1;
    ALOAD(B, cB);        // issue next chunk's loads (covered by ACOMP(A))
    ACOMP(A, cA);
    ALOAD(A, cA + 2);    // final iteration clamps to last rows — harmless
    ACOMP(B, cB);
  }

  #pragma unroll
  for (int o = 32; o; o >>= 1) fin = fmaxf(fin, __shfl_xor(fin, o));
  if (lane == 0) {
    float last = pbb[(size_t)dstar * DSTRIDE + 1 + ul];   // log2 domain
    lls[b] = fin + last;
  }
  __syncthreads();
  if (tid == 0)
    out[0] = -(lls[0] + lls[1] + lls[2] + lls[3]) * (LN2 * 0.25f);
}

// ---------------- launcher ----------------
extern "C" void kernel_launch(void* const* d_in, const int* in_sizes, int n_in,
                              void* d_out, int out_size, void* d_ws, size_t ws_size,
                              hipStream_t stream) {
  const float* enc = (const float*)d_in[0];
  const float* dec = (const float*)d_in[1];
  const float* Wf  = (const float*)d_in[2];
  const float* bfv = (const float*)d_in[3];
  const float* Wp  = (const float*)d_in[4];
  const float* bp  = (const float*)d_in[5];
  const int* targets = (const int*)d_in[6];
  const int* ilen    = (const int*)d_in[7];
  const int* ulen    = (const int*)d_in[8];
  float* out = (float*)d_out;
  char* ws = (char*)d_ws;

  short* WfB   = (short*)(ws + 0);          //   655360 B (packed)
  short* WpB   = (short*)(ws + 655360);     //  1048576 B (packed) -> 1703936
  short* epB   = (short*)(ws + 1703936);    //  1228800 B (bf16)   -> 2932736
  short* dpB   = (short*)(ws + 2932736);    //   331776 B (bf16)   -> 3264512
  float* lpb_p = (float*)(ws + 3264512);    //   498560 B (4*380*82) -> 3763072
  float* lpe_p = (float*)(ws + 3763072);    //   497248 B (4*379*82) -> 4260320
  const int FILL_N4 = (4 * NDIAG_B * DSTRIDE + 4 * NDIAG_E * DSTRIDE) / 4; // 62238

  fill_kernel<<<(FILL_N4 + 255) / 256, 256, 0, stream>>>(lpb_p, FILL_N4);
  cvt_kernel<<<832, 256, 0, stream>>>(Wf, Wp, WfB, WpB);
  proj_kernel<<<50, 256, 0, stream>>>(enc, dec, WfB, bfv, epB, dpB);
  joint_kernel<<<(NROWS + JROWS - 1) / JROWS, 512, 65536, stream>>>(epB, dpB, WpB, bp, targets, lpb_p, lpe_p);
  alpha_kernel<<<1, 256, 0, stream>>>(lpb_p, lpe_p, ilen, ulen, out);
}

// Round 12
// 198.874 us; speedup vs baseline: 1.1791x; 1.0974x over previous
//
#include <hip/hip_runtime.h>

#define B_DIM 4
#define T_DIM 300
#define U_DIM 80
#define UP1   81
#define V_DIM 1024
#define NINNER 512
#define NROWS (B_DIM * T_DIM * UP1)   /* 97200 */
#define EP_ROWS (B_DIM * T_DIM)       /* 1200 */
#define DP_ROWS (B_DIM * UP1)         /* 324 */
#define NDIAG 380                      /* t+u diagonals */
#define ZSTR  168                      /* Z row stride in floats: 4 pad + 162, 16B-aligned */
#define ZROWS (B_DIM * NDIAG + 8)      /* + 8 NEG slack rows (no-clamp ALOAD) */
#define WF_PART 163840                 /* 512 cols x 320 k, per half of Wf */
#define LOG2E 1.44269504088896341f
#define LN2   0.69314718055994531f
#define NEGF  -1e30f

typedef float f32x4 __attribute__((ext_vector_type(4)));
typedef short short8 __attribute__((ext_vector_type(8)));
typedef short short4v __attribute__((ext_vector_type(4)));
typedef __bf16 bf16x8 __attribute__((ext_vector_type(8)));

static __device__ __forceinline__ short f2bf(float f) {
  return (short)__builtin_bit_cast(unsigned short, (__bf16)f);  // native cvt (RNE)
}
static __device__ __forceinline__ float bf2f(short s) {
  unsigned int u = ((unsigned int)(unsigned short)s) << 16;
  return __builtin_bit_cast(float, u);
}
static __device__ __forceinline__ float tanh_fast(float x) {
  float e = __builtin_amdgcn_exp2f(x * 2.88539008177792681f); // exp(2x)
  return 1.0f - 2.0f * __builtin_amdgcn_rcpf(e + 1.0f);
}
// base-2 logsumexp of 2 terms (finite-NEG safe)
static __device__ __forceinline__ float lse2_2(float a, float b) {
  float mx = fmaxf(a, b), mn = fminf(a, b);
  return mx + __builtin_amdgcn_logf(1.0f + __builtin_amdgcn_exp2f(mn - mx));
}
// DPP wave_ror:1 — dst[i] = src[(i+63)&63]; VALU pipe, no LDS unit (r11).
static __device__ __forceinline__ float ror1f(float x) {
  int r = __builtin_amdgcn_update_dpp(0, __builtin_bit_cast(int, x),
                                      0x13C /*WAVE_ROR1*/, 0xF, 0xF, true);
  return __builtin_bit_cast(float, r);
}
static __device__ __forceinline__ float readlanef(float x, int l) {
  return __builtin_bit_cast(float,
      __builtin_amdgcn_readlane(__builtin_bit_cast(int, x), l));
}
// 16B load at 4B alignment (Z operand quads sit at odd float indices)
static __device__ __forceinline__ f32x4 load4u(const float* p) {
  f32x4 v;
  __builtin_memcpy(&v, p, 16);
  return v;
}

// ---------------- Kernel 0: weight cvt/pack + Z NEG-prefill (fused r12) -----
// B-matrix element (c,k) -> frag-linear pack (r5). Tail blocks fill Z with NEG.
#define CVT_NF 81920
#define CVT_NP 131072
#define FILL_N4 ((ZROWS * ZSTR) / 4)   /* 64176 */
__global__ __launch_bounds__(256) void cvt_kernel(
    const float* __restrict__ Wf, const float* __restrict__ Wp,
    short* __restrict__ WfB, short* __restrict__ WpB, float* __restrict__ Z) {
  int idx = blockIdx.x * 256 + threadIdx.x;
  if (idx < CVT_NF) {
    float4 v = ((const float4*)Wf)[idx];
    int flat = idx * 4;
    int c = flat / 640;
    int kc = flat - c * 640;
    int part = (kc >= 320);
    int k0 = kc - (part ? 320 : 0);
    int dest = (part ? WF_PART : 0)
             + ((c >> 4) * 10 + (k0 >> 5)) * 512
             + (((k0 >> 3) & 3) * 16 + (c & 15)) * 8 + (k0 & 7);
    short4v o;
    o[0] = f2bf(v.x); o[1] = f2bf(v.y); o[2] = f2bf(v.z); o[3] = f2bf(v.w);
    *(short4v*)(WfB + dest) = o;
  } else if (idx < CVT_NF + CVT_NP) {
    int j = idx - CVT_NF;
    float4 v = ((const float4*)Wp)[j];
    int flat = j * 4;
    int c = flat >> 9;
    int k0 = flat & 511;
    int dest = ((c >> 4) * 16 + (k0 >> 5)) * 512
             + (((k0 >> 3) & 3) * 16 + (c & 15)) * 8 + (k0 & 7);
    short4v o;
    o[0] = f2bf(v.x); o[1] = f2bf(v.y); o[2] = f2bf(v.z); o[3] = f2bf(v.w);
    *(short4v*)(WpB + dest) = o;
  } else {
    int i = idx - (CVT_NF + CVT_NP);
    if (i < FILL_N4) ((f32x4*)Z)[i] = (f32x4){NEGF, NEGF, NEGF, NEGF};
  }
}

// ---------------- Kernel 1: enc/dec projections (MFMA bf16) ----------------
// NOTE: no min-waves arg — min-waves>=4 on MFMA kernels splits the unified
// RF (Arch 64 / AGPR 64) and spills (r2/r3).
#define EP_BLOCKS 19
__global__ __launch_bounds__(256) void proj_kernel(
    const float* __restrict__ enc, const float* __restrict__ dec,
    const short* __restrict__ WfB, const float* __restrict__ bfv,
    short* __restrict__ epB, short* __restrict__ dpB) {
  const int half = blockIdx.x & 1;
  const int ob = blockIdx.x >> 1;
  const bool is_dp = (ob >= EP_BLOCKS);
  const int row0 = (is_dp ? ob - EP_BLOCKS : ob) * 64;
  const int nrows = is_dp ? DP_ROWS : EP_ROWS;
  const float* __restrict__ src = is_dp ? dec : enc;
  const short* __restrict__ bb = WfB + (is_dp ? WF_PART : 0);  // packed
  short* __restrict__ out = is_dp ? dpB : epB;

  __shared__ short As[64 * 320];  // 40 KB, XOR-swizzled
  const int tid = threadIdx.x;

  #pragma unroll
  for (int it = 0; it < 10; ++it) {
    int chunk = it * 256 + tid;        // 2560 chunks of 8 elems
    int m = chunk / 40;
    int c = chunk - m * 40;
    int r = row0 + m;
    short8 hv;
    #pragma unroll
    for (int j = 0; j < 8; ++j) hv[j] = 0;
    if (r < nrows) {
      const float* p = src + (size_t)r * 320 + c * 8;
      float4 a0 = *(const float4*)p;
      float4 a1 = *(const float4*)(p + 4);
      hv[0] = f2bf(a0.x); hv[1] = f2bf(a0.y); hv[2] = f2bf(a0.z); hv[3] = f2bf(a0.w);
      hv[4] = f2bf(a1.x); hv[5] = f2bf(a1.y); hv[6] = f2bf(a1.z); hv[7] = f2bf(a1.w);
    }
    int off = (m * 640 + c * 16) ^ ((m & 7) << 4);
    *(short8*)((char*)As + off) = hv;
  }
  __syncthreads();

  const int lane = tid & 63, wid = tid >> 6;
  const int lr = lane & 15, g = lane >> 4;

  int lin[4], xm[4];
  #pragma unroll
  for (int mf = 0; mf < 4; ++mf) {
    int row = mf * 16 + lr;
    lin[mf] = row * 640 + g * 16;
    xm[mf] = (row & 7) << 4;
  }

  const int n0 = half * 256 + wid * 64;
  const short* bptr[4];
  float bfc[4];
  #pragma unroll
  for (int nf2 = 0; nf2 < 4; ++nf2) {
    bptr[nf2] = bb + (n0 / 16 + nf2) * 5120 + lane * 8;   // frag-linear
    bfc[nf2] = is_dp ? bfv[n0 + nf2 * 16 + lr] : 0.f;
  }
  f32x4 acc[4][4];
  #pragma unroll
  for (int mf = 0; mf < 4; ++mf)
    #pragma unroll
    for (int nf2 = 0; nf2 < 4; ++nf2)
      acc[mf][nf2] = (f32x4){0.f, 0.f, 0.f, 0.f};

  #pragma unroll 2
  for (int kk = 0; kk < 10; ++kk) {
    bf16x8 av[4], bv[4];
    #pragma unroll
    for (int mf = 0; mf < 4; ++mf) {
      int off = (lin[mf] + (kk << 6)) ^ xm[mf];
      av[mf] = __builtin_bit_cast(bf16x8, *(const short8*)((const char*)As + off));
    }
    #pragma unroll
    for (int nf2 = 0; nf2 < 4; ++nf2)
      bv[nf2] = __builtin_bit_cast(bf16x8, *(const short8*)(bptr[nf2] + kk * 512));
    #pragma unroll
    for (int mf = 0; mf < 4; ++mf)
      #pragma unroll
      for (int nf2 = 0; nf2 < 4; ++nf2)
        acc[mf][nf2] = __builtin_amdgcn_mfma_f32_16x16x32_bf16(av[mf], bv[nf2], acc[mf][nf2], 0, 0, 0);
  }
  #pragma unroll
  for (int mf = 0; mf < 4; ++mf)
    #pragma unroll
    for (int nf2 = 0; nf2 < 4; ++nf2)
      #pragma unroll
      for (int rr = 0; rr < 4; ++rr) {
        int rowl = mf * 16 + g * 4 + rr;
        int grow = row0 + rowl;
        if (grow < nrows) {
          int col = n0 + nf2 * 16 + lr;
          out[(size_t)grow * NINNER + col] = f2bf(acc[mf][nf2][rr] + bfc[nf2]);
        }
      }
}

// ---------------- Kernel 2: fused joint + log-softmax slices ----------------
// r9-champion structure (JROWS 64, mf=4, 64KB LDS). Base-2 softmax, LOG2-
// domain outputs into INTERLEAVED padded Z layout (r12): row (b,d=t+u),
// Z[row][4+2u] = lp_blank, Z[row][4+2u+1] = lp_emit. T5 setprio on MFMA.
#define JROWS 64
__global__ __launch_bounds__(512) void joint_kernel(
    const short* __restrict__ epB, const short* __restrict__ dpB,
    const short* __restrict__ WpB, const float* __restrict__ bp,
    const int* __restrict__ tgt, float* __restrict__ Z) {
  extern __shared__ char hbuf[];  // 64 * 512 * 2 = 65536 B
  __shared__ int ep_off[JROWS], dp_off[JROWS], bld_off[JROWS], eld_off[JROWS], tgt_s[JROWS];
  __shared__ float l0_s[JROWS], lt_s[JROWS];
  __shared__ float ws_s[8][JROWS];

  const int tid = threadIdx.x;
  const int row0 = blockIdx.x * JROWS;

  if (tid < JROWS) {
    int gr = row0 + tid;
    if (gr < NROWS) {
      int b = gr / (T_DIM * UP1);
      int rem = gr - b * (T_DIM * UP1);
      int t = rem / UP1;
      int u = rem - t * UP1;
      ep_off[tid] = (b * T_DIM + t) * NINNER;
      dp_off[tid] = (b * UP1 + u) * NINNER;
      int zrow = (b * NDIAG + (t + u)) * ZSTR;
      bld_off[tid] = zrow + 4 + 2 * u;
      eld_off[tid] = (u < U_DIM) ? (zrow + 4 + 2 * u + 1) : -1;
      tgt_s[tid] = (u < U_DIM) ? tgt[b * U_DIM + u] : 0;
    } else {
      ep_off[tid] = 0; dp_off[tid] = 0; bld_off[tid] = -1; eld_off[tid] = -1; tgt_s[tid] = 0;
    }
    l0_s[tid] = 0.f; lt_s[tid] = 0.f;
  }
  __syncthreads();

  // Phase A: h = tanh(ep+dp) into LDS (bf16 in, bf16 out, swizzled)
  #pragma unroll 2
  for (int it = 0; it < 8; ++it) {
    int chunk = it * 512 + tid;    // 4096 chunks of 8
    int m = chunk >> 6, c = chunk & 63;
    short8 hv;
    #pragma unroll
    for (int j = 0; j < 8; ++j) hv[j] = 0;
    if (bld_off[m] >= 0) {
      short8 ev = *(const short8*)(epB + ep_off[m] + c * 8);
      short8 dv = *(const short8*)(dpB + dp_off[m] + c * 8);
      #pragma unroll
      for (int j = 0; j < 8; ++j)
        hv[j] = f2bf(tanh_fast(bf2f(ev[j]) + bf2f(dv[j])));
    }
    int off = ((m << 10) + (c << 4)) ^ ((m & 7) << 4);
    *(short8*)(hbuf + off) = hv;
  }
  __syncthreads();

  const int lane = tid & 63, wid = tid >> 6;
  const int lr = lane & 15, g = lane >> 4;

  int lin[4], xm[4];
  #pragma unroll
  for (int mf = 0; mf < 4; ++mf) {
    int row = mf * 16 + lr;
    lin[mf] = (row << 10) + (g << 4);
    xm[mf] = (row & 7) << 4;
  }
  int tv[4][4];
  #pragma unroll
  for (int mf = 0; mf < 4; ++mf)
    #pragma unroll
    for (int rr = 0; rr < 4; ++rr)
      tv[mf][rr] = tgt_s[mf * 16 + g * 4 + rr];

  float rsum[4][4];
  #pragma unroll
  for (int mf = 0; mf < 4; ++mf)
    #pragma unroll
    for (int rr = 0; rr < 4; ++rr) rsum[mf][rr] = 0.f;

  #pragma unroll
  for (int sc = 0; sc < 2; ++sc) {
    const int n0 = wid * 128 + sc * 64;
    const short* bptr[4];
    float bpv[4];
    #pragma unroll
    for (int nf = 0; nf < 4; ++nf) {
      bptr[nf] = WpB + (n0 / 16 + nf) * 8192 + lane * 8;   // frag-linear
      bpv[nf] = bp[n0 + nf * 16 + lr] * LOG2E;             // scaled bias
    }
    f32x4 acc[4][4];
    #pragma unroll
    for (int mf = 0; mf < 4; ++mf)
      #pragma unroll
      for (int nf = 0; nf < 4; ++nf)
        acc[mf][nf] = (f32x4){0.f, 0.f, 0.f, 0.f};

    #pragma unroll 2
    for (int kk = 0; kk < 16; ++kk) {
      bf16x8 av[4], bv[4];
      #pragma unroll
      for (int mf = 0; mf < 4; ++mf) {
        int off = (lin[mf] + (kk << 6)) ^ xm[mf];
        av[mf] = __builtin_bit_cast(bf16x8, *(const short8*)(hbuf + off));
      }
      #pragma unroll
      for (int nf = 0; nf < 4; ++nf)
        bv[nf] = __builtin_bit_cast(bf16x8, *(const short8*)(bptr[nf] + kk * 512));
      __builtin_amdgcn_s_setprio(1);          // T5: favor MFMA burst
      #pragma unroll
      for (int mf = 0; mf < 4; ++mf)
        #pragma unroll
        for (int nf = 0; nf < 4; ++nf)
          acc[mf][nf] = __builtin_amdgcn_mfma_f32_16x16x32_bf16(av[mf], bv[nf], acc[mf][nf], 0, 0, 0);
      __builtin_amdgcn_s_setprio(0);
    }
    // fold: base-2 sum-of-exp2 over this 64-col subchunk (scaled logits)
    #pragma unroll
    for (int mf = 0; mf < 4; ++mf)
      #pragma unroll
      for (int rr = 0; rr < 4; ++rr) {
        float x0 = __builtin_fmaf(acc[mf][0][rr], LOG2E, bpv[0]);
        float x1 = __builtin_fmaf(acc[mf][1][rr], LOG2E, bpv[1]);
        float x2 = __builtin_fmaf(acc[mf][2][rr], LOG2E, bpv[2]);
        float x3 = __builtin_fmaf(acc[mf][3][rr], LOG2E, bpv[3]);
        int rowl = mf * 16 + g * 4 + rr;
        if (wid == 0 && sc == 0 && lr == 0) l0_s[rowl] = x0;  // v = 0 (scaled)
        int dtv = tv[mf][rr] - n0;
        if (dtv >= 0 && dtv < 64 && (dtv & 15) == lr) {
          int nfi = dtv >> 4;
          lt_s[rowl] = (nfi == 0) ? x0 : (nfi == 1) ? x1 : (nfi == 2) ? x2 : x3;
        }
        rsum[mf][rr] += __builtin_amdgcn_exp2f(x0) + __builtin_amdgcn_exp2f(x1)
                      + __builtin_amdgcn_exp2f(x2) + __builtin_amdgcn_exp2f(x3);
      }
  }
  // add-butterfly across the 16 lanes of each group
  #pragma unroll
  for (int mf = 0; mf < 4; ++mf)
    #pragma unroll
    for (int rr = 0; rr < 4; ++rr) {
      float s_ = rsum[mf][rr];
      #pragma unroll
      for (int o = 1; o < 16; o <<= 1) s_ += __shfl_xor(s_, o);
      if (lr == 0) ws_s[wid][mf * 16 + g * 4 + rr] = s_;
    }
  __syncthreads();
  if (tid < JROWS) {
    int bo = bld_off[tid];
    if (bo >= 0) {
      float S = 0.f;
      #pragma unroll
      for (int w = 0; w < 8; ++w) S += ws_s[w][tid];
      float lse2v = __builtin_amdgcn_logf(S);   // log2
      Z[bo] = l0_s[tid] - lse2v;                // LOG2 DOMAIN, blank slot
      int eo = eld_off[tid];
      if (eo >= 0) Z[eo] = lt_s[tid] - lse2v;   // emit slot
    }
  }
}

// ---------------- Kernel 3: alpha DP — float4 operand quads (r12) -----------
// r11 residue diagnosed as ALOAD: 64 scalar loads/chunk + per-load address
// arith + remote-L2/L3 source. r12: interleaved Z rows make each (row,slot)'s
// 4 operands {e1m,b1m,e1,b1} one contiguous 16B load at Z[row]+1+2u (4B-
// aligned). 16 loads/chunk, compile-time row offsets (8 NEG slack rows, no
// clamp). Chain/captures identical to validated r9/r11. LOG2 domain.
#define ACH 8
#define NCH 48   /* s1 reaches 383 >= dstar max 379; slack rows cover tail */
__global__ __launch_bounds__(256) void alpha_kernel(
    const float* __restrict__ Z,
    const int* __restrict__ ilen, const int* __restrict__ ulen_,
    float* __restrict__ out) {
  __shared__ float lls[B_DIM];
  const int tid = threadIdx.x;
  const int b = tid >> 6;
  const int lane = tid & 63;
  const float NEG = NEGF;
  const int tl = ilen[b], ul = ulen_[b];
  const int dstar = tl - 1 + ul;          // final-cell diagonal

  const int u0 = lane;           // slot 0: u = 0..63
  const int u1 = 64 + lane;      // slot 1: u = 64..80 (lane < 17)
  const bool act1 = (u1 <= 80);
  const int uc1 = act1 ? u1 : 80;

  const float* Zb = Z + (size_t)b * (NDIAG * ZSTR);

  f32x4 Aq0[ACH], Aq1[ACH], Bq0[ACH], Bq1[ACH];

  #define ALOAD(P, c)                                                        \
    {                                                                        \
      const float* base0 = Zb + (c) * (ACH * ZSTR) + 1 + 2 * u0;             \
      const float* base1 = Zb + (c) * (ACH * ZSTR) + 1 + 2 * uc1;            \
      _Pragma("unroll")                                                      \
      for (int j = 0; j < ACH; ++j) {                                        \
        P##q0[j] = load4u(base0 + j * ZSTR);                                 \
        P##q1[j] = load4u(base1 + j * ZSTR);                                 \
      }                                                                      \
    }

  #define ACOMP(P, c)                                                        \
    {                                                                        \
      _Pragma("unroll")                                                      \
      for (int q = 0; q < ACH / 2; ++q) {                                    \
        const int j = 2 * q;                                                 \
        const int s1 = (c) * ACH + j + 1;                                    \
        /* neighbor alphas via DPP (VALU pipe) */                            \
        float a63 = readlanef(pa0, 63), a62 = readlanef(pa0, 62);            \
        float s0m1 = ror1f(pa0);                                             \
        float s0m2 = ror1f(s0m1);                                            \
        float s1m1r = ror1f(pa1);                                            \
        float s1m2r = ror1f(s1m1r);                                          \
        float s1m1 = (lane == 0) ? a63 : s1m1r;                              \
        float s1m2 = (lane == 0) ? a62 : ((lane == 1) ? a63 : s1m2r);        \
        float na0, na1;                                                      \
        { /* slot 0 — v={e1m,b1m,e1,b1}, w=next row */                       \
          f32x4 v = P##q0[j], w = P##q0[j + 1];                              \
          float T1 = v[3] + w[3];                                            \
          float T2 = lse2_2(v[2] + w[3], v[1] + w[2]);                       \
          float T3 = v[0] + w[2];                                            \
          float p0 = pa0 + T1;                                               \
          float p1 = s0m1 + T2;                                              \
          float p2 = s0m2 + T3;                                              \
          float mx = fmaxf(fmaxf(p0, p1), p2);                               \
          float ss = __builtin_amdgcn_exp2f(p0 - mx)                         \
                   + __builtin_amdgcn_exp2f(p1 - mx)                         \
                   + __builtin_amdgcn_exp2f(p2 - mx);                        \
          na0 = fmaxf(mx + __builtin_amdgcn_logf(ss), NEG);                  \
        }                                                                    \
        { /* slot 1 */                                                       \
          f32x4 v = P##q1[j], w = P##q1[j + 1];                              \
          float T1 = v[3] + w[3];                                            \
          float T2 = lse2_2(v[2] + w[3], v[1] + w[2]);                       \
          float T3 = v[0] + w[2];                                            \
          float p0 = pa1 + T1;                                               \
          float p1 = s1m1 + T2;                                              \
          float p2 = s1m2 + T3;                                              \
          float mx = fmaxf(fmaxf(p0, p1), p2);                               \
          float ss = __builtin_amdgcn_exp2f(p0 - mx)                         \
                   + __builtin_amdgcn_exp2f(p1 - mx)                         \
                   + __builtin_amdgcn_exp2f(p2 - mx);                        \
          na1 = fmaxf(mx + __builtin_amdgcn_logf(ss), NEG);                  \
        }                                                                    \
        if (s1 == dstar) { /* odd-diagonal final capture */                  \
          float vo0 = lse2_2(pa0 + P##q0[j][3], s0m1 + P##q0[j][2]);         \
          if (u0 == ul) fin = vo0;                                           \
          float vo1 = lse2_2(pa1 + P##q1[j][3], s1m1 + P##q1[j][2]);         \
          if (act1 && u1 == ul) fin = vo1;                                   \
        }                                                                    \
        pa0 = na0; pa1 = na1;                                                \
        if (s1 + 1 == dstar) { /* even-diagonal final capture */             \
          if (u0 == ul) fin = pa0;                                           \
          if (act1 && u1 == ul) fin = pa1;                                   \
        }                                                                    \
      }                                                                      \
    }

  float pa0 = (u0 == 0) ? 0.f : NEG;  // alpha on diag 0 (log2 domain)
  float pa1 = NEG;
  float fin = NEG;
  if (dstar == 0 && u0 == ul) fin = pa0;   // tl=1, ul=0 corner

  ALOAD(A, 0);
  for (int p = 0; p < NCH / 2; ++p) {
    const int cA = 2 * p, cB = 2 * p + 1;
    ALOAD(B, cB);        // issue next chunk's loads (covered by ACOMP(A))
    ACOMP(A, cA);
    ALOAD(A, cA + 2);    // tail chunks read NEG slack rows — harmless
    ACOMP(B, cB);
  }

  #pragma unroll
  for (int o = 32; o; o >>= 1) fin = fmaxf(fin, __shfl_xor(fin, o));
  if (lane == 0) {
    float last = Zb[(size_t)dstar * ZSTR + 4 + 2 * ul];   // blank, log2 domain
    lls[b] = fin + last;
  }
  __syncthreads();
  if (tid == 0)
    out[0] = -(lls[0] + lls[1] + lls[2] + lls[3]) * (LN2 * 0.25f);
}

// ---------------- launcher ----------------
extern "C" void kernel_launch(void* const* d_in, const int* in_sizes, int n_in,
                              void* d_out, int out_size, void* d_ws, size_t ws_size,
                              hipStream_t stream) {
  const float* enc = (const float*)d_in[0];
  const float* dec = (const float*)d_in[1];
  const float* Wf  = (const float*)d_in[2];
  const float* bfv = (const float*)d_in[3];
  const float* Wp  = (const float*)d_in[4];
  const float* bp  = (const float*)d_in[5];
  const int* targets = (const int*)d_in[6];
  const int* ilen    = (const int*)d_in[7];
  const int* ulen    = (const int*)d_in[8];
  float* out = (float*)d_out;
  char* ws = (char*)d_ws;

  short* WfB = (short*)(ws + 0);          //   655360 B (packed)
  short* WpB = (short*)(ws + 655360);     //  1048576 B (packed) -> 1703936
  short* epB = (short*)(ws + 1703936);    //  1228800 B (bf16)   -> 2932736
  short* dpB = (short*)(ws + 2932736);    //   331776 B (bf16)   -> 3264512
  float* Z   = (float*)(ws + 3264512);    //  1026816 B (1528*168*4) -> 4291328

  // cvt+pack (832 blocks) fused with Z NEG-prefill (251 tail blocks)
  cvt_kernel<<<1083, 256, 0, stream>>>(Wf, Wp, WfB, WpB, Z);
  proj_kernel<<<50, 256, 0, stream>>>(enc, dec, WfB, bfv, epB, dpB);
  joint_kernel<<<(NROWS + JROWS - 1) / JROWS, 512, 65536, stream>>>(epB, dpB, WpB, bp, targets, Z);
  alpha_kernel<<<1, 256, 0, stream>>>(Z, ilen, ulen, out);
}

// Round 13
// 190.765 us; speedup vs baseline: 1.2292x; 1.0425x over previous
//
#include <hip/hip_runtime.h>

#define B_DIM 4
#define T_DIM 300
#define U_DIM 80
#define UP1   81
#define V_DIM 1024
#define NINNER 512
#define NROWS (B_DIM * T_DIM * UP1)   /* 97200 */
#define EP_ROWS (B_DIM * T_DIM)       /* 1200 */
#define DP_ROWS (B_DIM * UP1)         /* 324 */
#define NDIAG 380                      /* t+u diagonals */
#define ZSTR  168                      /* Z row stride in floats: 4 pad + 162, 16B-aligned */
#define ZROWS (B_DIM * NDIAG + 8)      /* + 8 NEG slack rows (no-clamp ALOAD) */
#define WF_PART 163840                 /* 512 cols x 320 k, per half of Wf */
#define LOG2E 1.44269504088896341f
#define LN2   0.69314718055994531f
#define NEGF  -1e30f

typedef float f32x4 __attribute__((ext_vector_type(4)));
typedef short short8 __attribute__((ext_vector_type(8)));
typedef short short4v __attribute__((ext_vector_type(4)));
typedef __bf16 bf16x8 __attribute__((ext_vector_type(8)));

static __device__ __forceinline__ short f2bf(float f) {
  return (short)__builtin_bit_cast(unsigned short, (__bf16)f);  // native cvt (RNE)
}
static __device__ __forceinline__ float bf2f(short s) {
  unsigned int u = ((unsigned int)(unsigned short)s) << 16;
  return __builtin_bit_cast(float, u);
}
static __device__ __forceinline__ float tanh_fast(float x) {
  float e = __builtin_amdgcn_exp2f(x * 2.88539008177792681f); // exp(2x)
  return 1.0f - 2.0f * __builtin_amdgcn_rcpf(e + 1.0f);
}
// base-2 logsumexp of 2 terms (finite-NEG safe)
static __device__ __forceinline__ float lse2_2(float a, float b) {
  float mx = fmaxf(a, b), mn = fminf(a, b);
  return mx + __builtin_amdgcn_logf(1.0f + __builtin_amdgcn_exp2f(mn - mx));
}
// DPP wave_ror:1 — dst[i] = src[(i+63)&63]; VALU pipe, no LDS unit (r11).
static __device__ __forceinline__ float ror1f(float x) {
  int r = __builtin_amdgcn_update_dpp(0, __builtin_bit_cast(int, x),
                                      0x13C /*WAVE_ROR1*/, 0xF, 0xF, true);
  return __builtin_bit_cast(float, r);
}
static __device__ __forceinline__ float readlanef(float x, int l) {
  return __builtin_bit_cast(float,
      __builtin_amdgcn_readlane(__builtin_bit_cast(int, x), l));
}
// 16B load at 4B alignment (Z operand quads sit at odd float indices)
static __device__ __forceinline__ f32x4 load4u(const float* p) {
  f32x4 v;
  __builtin_memcpy(&v, p, 16);
  return v;
}

// ---------------- Kernel 0: weight cvt/pack + Z NEG-prefill (fused r12) -----
#define CVT_NF 81920
#define CVT_NP 131072
#define FILL_N4 ((ZROWS * ZSTR) / 4)   /* 64176 */
__global__ __launch_bounds__(256) void cvt_kernel(
    const float* __restrict__ Wf, const float* __restrict__ Wp,
    short* __restrict__ WfB, short* __restrict__ WpB, float* __restrict__ Z) {
  int idx = blockIdx.x * 256 + threadIdx.x;
  if (idx < CVT_NF) {
    float4 v = ((const float4*)Wf)[idx];
    int flat = idx * 4;
    int c = flat / 640;
    int kc = flat - c * 640;
    int part = (kc >= 320);
    int k0 = kc - (part ? 320 : 0);
    int dest = (part ? WF_PART : 0)
             + ((c >> 4) * 10 + (k0 >> 5)) * 512
             + (((k0 >> 3) & 3) * 16 + (c & 15)) * 8 + (k0 & 7);
    short4v o;
    o[0] = f2bf(v.x); o[1] = f2bf(v.y); o[2] = f2bf(v.z); o[3] = f2bf(v.w);
    *(short4v*)(WfB + dest) = o;
  } else if (idx < CVT_NF + CVT_NP) {
    int j = idx - CVT_NF;
    float4 v = ((const float4*)Wp)[j];
    int flat = j * 4;
    int c = flat >> 9;
    int k0 = flat & 511;
    int dest = ((c >> 4) * 16 + (k0 >> 5)) * 512
             + (((k0 >> 3) & 3) * 16 + (c & 15)) * 8 + (k0 & 7);
    short4v o;
    o[0] = f2bf(v.x); o[1] = f2bf(v.y); o[2] = f2bf(v.z); o[3] = f2bf(v.w);
    *(short4v*)(WpB + dest) = o;
  } else {
    int i = idx - (CVT_NF + CVT_NP);
    if (i < FILL_N4) ((f32x4*)Z)[i] = (f32x4){NEGF, NEGF, NEGF, NEGF};
  }
}

// ---------------- Kernel 1: enc/dec projections (MFMA bf16) ----------------
// NOTE: no min-waves arg — min-waves>=4 on MFMA kernels splits the unified
// RF (Arch 64 / AGPR 64) and spills (r2/r3).
#define EP_BLOCKS 19
__global__ __launch_bounds__(256) void proj_kernel(
    const float* __restrict__ enc, const float* __restrict__ dec,
    const short* __restrict__ WfB, const float* __restrict__ bfv,
    short* __restrict__ epB, short* __restrict__ dpB) {
  const int half = blockIdx.x & 1;
  const int ob = blockIdx.x >> 1;
  const bool is_dp = (ob >= EP_BLOCKS);
  const int row0 = (is_dp ? ob - EP_BLOCKS : ob) * 64;
  const int nrows = is_dp ? DP_ROWS : EP_ROWS;
  const float* __restrict__ src = is_dp ? dec : enc;
  const short* __restrict__ bb = WfB + (is_dp ? WF_PART : 0);  // packed
  short* __restrict__ out = is_dp ? dpB : epB;

  __shared__ short As[64 * 320];  // 40 KB, XOR-swizzled
  const int tid = threadIdx.x;

  #pragma unroll
  for (int it = 0; it < 10; ++it) {
    int chunk = it * 256 + tid;        // 2560 chunks of 8 elems
    int m = chunk / 40;
    int c = chunk - m * 40;
    int r = row0 + m;
    short8 hv;
    #pragma unroll
    for (int j = 0; j < 8; ++j) hv[j] = 0;
    if (r < nrows) {
      const float* p = src + (size_t)r * 320 + c * 8;
      float4 a0 = *(const float4*)p;
      float4 a1 = *(const float4*)(p + 4);
      hv[0] = f2bf(a0.x); hv[1] = f2bf(a0.y); hv[2] = f2bf(a0.z); hv[3] = f2bf(a0.w);
      hv[4] = f2bf(a1.x); hv[5] = f2bf(a1.y); hv[6] = f2bf(a1.z); hv[7] = f2bf(a1.w);
    }
    int off = (m * 640 + c * 16) ^ ((m & 7) << 4);
    *(short8*)((char*)As + off) = hv;
  }
  __syncthreads();

  const int lane = tid & 63, wid = tid >> 6;
  const int lr = lane & 15, g = lane >> 4;

  int lin[4], xm[4];
  #pragma unroll
  for (int mf = 0; mf < 4; ++mf) {
    int row = mf * 16 + lr;
    lin[mf] = row * 640 + g * 16;
    xm[mf] = (row & 7) << 4;
  }

  const int n0 = half * 256 + wid * 64;
  const short* bptr[4];
  float bfc[4];
  #pragma unroll
  for (int nf2 = 0; nf2 < 4; ++nf2) {
    bptr[nf2] = bb + (n0 / 16 + nf2) * 5120 + lane * 8;   // frag-linear
    bfc[nf2] = is_dp ? bfv[n0 + nf2 * 16 + lr] : 0.f;
  }
  f32x4 acc[4][4];
  #pragma unroll
  for (int mf = 0; mf < 4; ++mf)
    #pragma unroll
    for (int nf2 = 0; nf2 < 4; ++nf2)
      acc[mf][nf2] = (f32x4){0.f, 0.f, 0.f, 0.f};

  #pragma unroll 2
  for (int kk = 0; kk < 10; ++kk) {
    bf16x8 av[4], bv[4];
    #pragma unroll
    for (int mf = 0; mf < 4; ++mf) {
      int off = (lin[mf] + (kk << 6)) ^ xm[mf];
      av[mf] = __builtin_bit_cast(bf16x8, *(const short8*)((const char*)As + off));
    }
    #pragma unroll
    for (int nf2 = 0; nf2 < 4; ++nf2)
      bv[nf2] = __builtin_bit_cast(bf16x8, *(const short8*)(bptr[nf2] + kk * 512));
    #pragma unroll
    for (int mf = 0; mf < 4; ++mf)
      #pragma unroll
      for (int nf2 = 0; nf2 < 4; ++nf2)
        acc[mf][nf2] = __builtin_amdgcn_mfma_f32_16x16x32_bf16(av[mf], bv[nf2], acc[mf][nf2], 0, 0, 0);
  }
  #pragma unroll
  for (int mf = 0; mf < 4; ++mf)
    #pragma unroll
    for (int nf2 = 0; nf2 < 4; ++nf2)
      #pragma unroll
      for (int rr = 0; rr < 4; ++rr) {
        int rowl = mf * 16 + g * 4 + rr;
        int grow = row0 + rowl;
        if (grow < nrows) {
          int col = n0 + nf2 * 16 + lr;
          out[(size_t)grow * NINNER + col] = f2bf(acc[mf][nf2][rr] + bfc[nf2]);
        }
      }
}

// ---------------- Kernel 2: fused joint + log-softmax slices ----------------
// r13: K-quarter software pipeline. Stage h in 4 K-quarters (128 K each,
// disjoint LDS regions). Quarter q+1's ep/dp loads + tanh interleave with
// sc0's GEMM on quarter q (stage loads issued BEFORE the MFMAs, tanh+write
// AFTER — T14 issue-early/write-late). One barrier per quarter. sc1 then runs
// all 16 kk barrier-free. Base-2 softmax, LOG2-domain outputs into
// interleaved padded Z (r12). setprio dropped (GEMM-lockstep null, m190).
#define JROWS 64
__global__ __launch_bounds__(512) void joint_kernel(
    const short* __restrict__ epB, const short* __restrict__ dpB,
    const short* __restrict__ WpB, const float* __restrict__ bp,
    const int* __restrict__ tgt, float* __restrict__ Z) {
  extern __shared__ char hbuf[];  // 64 * 512 * 2 = 65536 B
  __shared__ int ep_off[JROWS], dp_off[JROWS], bld_off[JROWS], eld_off[JROWS], tgt_s[JROWS];
  __shared__ float l0_s[JROWS], lt_s[JROWS];
  __shared__ float ws_s[8][JROWS];

  const int tid = threadIdx.x;
  const int row0 = blockIdx.x * JROWS;

  if (tid < JROWS) {
    int gr = row0 + tid;
    if (gr < NROWS) {
      int b = gr / (T_DIM * UP1);
      int rem = gr - b * (T_DIM * UP1);
      int t = rem / UP1;
      int u = rem - t * UP1;
      ep_off[tid] = (b * T_DIM + t) * NINNER;
      dp_off[tid] = (b * UP1 + u) * NINNER;
      int zrow = (b * NDIAG + (t + u)) * ZSTR;
      bld_off[tid] = zrow + 4 + 2 * u;
      eld_off[tid] = (u < U_DIM) ? (zrow + 4 + 2 * u + 1) : -1;
      tgt_s[tid] = (u < U_DIM) ? tgt[b * U_DIM + u] : 0;
    } else {
      // invalid rows: offsets 0 -> loads read valid memory; tanh is bounded,
      // outputs never written (bld_off<0), and MFMA rows are independent.
      ep_off[tid] = 0; dp_off[tid] = 0; bld_off[tid] = -1; eld_off[tid] = -1; tgt_s[tid] = 0;
    }
    l0_s[tid] = 0.f; lt_s[tid] = 0.f;
  }
  __syncthreads();

  // stage-geometry: thread covers rows m0 and m0+32 at col-unit cq (8 elems);
  // quarter q shifts global cols by q*128 elems and LDS bytes by q*256.
  const int m0 = tid >> 4;
  const int m1 = 32 + m0;
  const int cq = tid & 15;
  const short* pe0 = epB + ep_off[m0] + cq * 8;
  const short* pd0 = dpB + dp_off[m0] + cq * 8;
  const short* pe1 = epB + ep_off[m1] + cq * 8;
  const short* pd1 = dpB + dp_off[m1] + cq * 8;
  const int po0 = ((m0 << 10) + (cq << 4)) ^ ((m0 & 7) << 4);
  const int po1 = ((m1 << 10) + (cq << 4)) ^ ((m1 & 7) << 4);

  short8 sev0, sdv0, sev1, sdv1;
#define STAGE_LOAD(q)                                  \
  {                                                    \
    sev0 = *(const short8*)(pe0 + (q) * 128);          \
    sdv0 = *(const short8*)(pd0 + (q) * 128);          \
    sev1 = *(const short8*)(pe1 + (q) * 128);          \
    sdv1 = *(const short8*)(pd1 + (q) * 128);          \
  }
#define STAGE_WRITE(q)                                                \
  {                                                                   \
    short8 h0, h1;                                                    \
    _Pragma("unroll")                                                 \
    for (int j = 0; j < 8; ++j) {                                     \
      h0[j] = f2bf(tanh_fast(bf2f(sev0[j]) + bf2f(sdv0[j])));         \
      h1[j] = f2bf(tanh_fast(bf2f(sev1[j]) + bf2f(sdv1[j])));         \
    }                                                                 \
    *(short8*)(hbuf + po0 + (q) * 256) = h0;                          \
    *(short8*)(hbuf + po1 + (q) * 256) = h1;                          \
  }

  STAGE_LOAD(0)
  STAGE_WRITE(0)
  __syncthreads();   // quarter 0 resident

  const int lane = tid & 63, wid = tid >> 6;
  const int lr = lane & 15, g = lane >> 4;

  int lin[4], xm[4];
  #pragma unroll
  for (int mf = 0; mf < 4; ++mf) {
    int row = mf * 16 + lr;
    lin[mf] = (row << 10) + (g << 4);
    xm[mf] = (row & 7) << 4;
  }
  int tv[4][4];
  #pragma unroll
  for (int mf = 0; mf < 4; ++mf)
    #pragma unroll
    for (int rr = 0; rr < 4; ++rr)
      tv[mf][rr] = tgt_s[mf * 16 + g * 4 + rr];

  float rsum[4][4];
  #pragma unroll
  for (int mf = 0; mf < 4; ++mf)
    #pragma unroll
    for (int rr = 0; rr < 4; ++rr) rsum[mf][rr] = 0.f;

  // ---- sc = 0: GEMM on quarters, pipelined with staging of quarters 1..3 --
  {
    const int n0 = wid * 128;
    const short* bptr[4];
    float bpv[4];
    #pragma unroll
    for (int nf = 0; nf < 4; ++nf) {
      bptr[nf] = WpB + (n0 / 16 + nf) * 8192 + lane * 8;   // frag-linear
      bpv[nf] = bp[n0 + nf * 16 + lr] * LOG2E;             // scaled bias
    }
    f32x4 acc[4][4];
    #pragma unroll
    for (int mf = 0; mf < 4; ++mf)
      #pragma unroll
      for (int nf = 0; nf < 4; ++nf)
        acc[mf][nf] = (f32x4){0.f, 0.f, 0.f, 0.f};

    #pragma unroll
    for (int qq = 0; qq < 4; ++qq) {
      if (qq < 3) STAGE_LOAD(qq + 1)           // issue early (latency hides)
      #pragma unroll
      for (int i = 0; i < 4; ++i) {
        const int kk = qq * 4 + i;
        bf16x8 av[4], bv[4];
        #pragma unroll
        for (int mf = 0; mf < 4; ++mf) {
          int off = (lin[mf] + (kk << 6)) ^ xm[mf];
          av[mf] = __builtin_bit_cast(bf16x8, *(const short8*)(hbuf + off));
        }
        #pragma unroll
        for (int nf = 0; nf < 4; ++nf)
          bv[nf] = __builtin_bit_cast(bf16x8, *(const short8*)(bptr[nf] + kk * 512));
        #pragma unroll
        for (int mf = 0; mf < 4; ++mf)
          #pragma unroll
          for (int nf = 0; nf < 4; ++nf)
            acc[mf][nf] = __builtin_amdgcn_mfma_f32_16x16x32_bf16(av[mf], bv[nf], acc[mf][nf], 0, 0, 0);
      }
      if (qq < 3) {
        STAGE_WRITE(qq + 1)                    // write late, then publish
        __syncthreads();
      }
    }
    // fold sc0: base-2 sum-of-exp2 (scaled logits)
    #pragma unroll
    for (int mf = 0; mf < 4; ++mf)
      #pragma unroll
      for (int rr = 0; rr < 4; ++rr) {
        float x0 = __builtin_fmaf(acc[mf][0][rr], LOG2E, bpv[0]);
        float x1 = __builtin_fmaf(acc[mf][1][rr], LOG2E, bpv[1]);
        float x2 = __builtin_fmaf(acc[mf][2][rr], LOG2E, bpv[2]);
        float x3 = __builtin_fmaf(acc[mf][3][rr], LOG2E, bpv[3]);
        int rowl = mf * 16 + g * 4 + rr;
        if (wid == 0 && lr == 0) l0_s[rowl] = x0;  // v = 0 (scaled)
        int dtv = tv[mf][rr] - n0;
        if (dtv >= 0 && dtv < 64 && (dtv & 15) == lr) {
          int nfi = dtv >> 4;
          lt_s[rowl] = (nfi == 0) ? x0 : (nfi == 1) ? x1 : (nfi == 2) ? x2 : x3;
        }
        rsum[mf][rr] += __builtin_amdgcn_exp2f(x0) + __builtin_amdgcn_exp2f(x1)
                      + __builtin_amdgcn_exp2f(x2) + __builtin_amdgcn_exp2f(x3);
      }
  }

  // ---- sc = 1: plain GEMM, all quarters resident -------------------------
  {
    const int n0 = wid * 128 + 64;
    const short* bptr[4];
    float bpv[4];
    #pragma unroll
    for (int nf = 0; nf < 4; ++nf) {
      bptr[nf] = WpB + (n0 / 16 + nf) * 8192 + lane * 8;
      bpv[nf] = bp[n0 + nf * 16 + lr] * LOG2E;
    }
    f32x4 acc[4][4];
    #pragma unroll
    for (int mf = 0; mf < 4; ++mf)
      #pragma unroll
      for (int nf = 0; nf < 4; ++nf)
        acc[mf][nf] = (f32x4){0.f, 0.f, 0.f, 0.f};

    #pragma unroll 2
    for (int kk = 0; kk < 16; ++kk) {
      bf16x8 av[4], bv[4];
      #pragma unroll
      for (int mf = 0; mf < 4; ++mf) {
        int off = (lin[mf] + (kk << 6)) ^ xm[mf];
        av[mf] = __builtin_bit_cast(bf16x8, *(const short8*)(hbuf + off));
      }
      #pragma unroll
      for (int nf = 0; nf < 4; ++nf)
        bv[nf] = __builtin_bit_cast(bf16x8, *(const short8*)(bptr[nf] + kk * 512));
      #pragma unroll
      for (int mf = 0; mf < 4; ++mf)
        #pragma unroll
        for (int nf = 0; nf < 4; ++nf)
          acc[mf][nf] = __builtin_amdgcn_mfma_f32_16x16x32_bf16(av[mf], bv[nf], acc[mf][nf], 0, 0, 0);
    }
    #pragma unroll
    for (int mf = 0; mf < 4; ++mf)
      #pragma unroll
      for (int rr = 0; rr < 4; ++rr) {
        float x0 = __builtin_fmaf(acc[mf][0][rr], LOG2E, bpv[0]);
        float x1 = __builtin_fmaf(acc[mf][1][rr], LOG2E, bpv[1]);
        float x2 = __builtin_fmaf(acc[mf][2][rr], LOG2E, bpv[2]);
        float x3 = __builtin_fmaf(acc[mf][3][rr], LOG2E, bpv[3]);
        int rowl = mf * 16 + g * 4 + rr;
        int dtv = tv[mf][rr] - n0;
        if (dtv >= 0 && dtv < 64 && (dtv & 15) == lr) {
          int nfi = dtv >> 4;
          lt_s[rowl] = (nfi == 0) ? x0 : (nfi == 1) ? x1 : (nfi == 2) ? x2 : x3;
        }
        rsum[mf][rr] += __builtin_amdgcn_exp2f(x0) + __builtin_amdgcn_exp2f(x1)
                      + __builtin_amdgcn_exp2f(x2) + __builtin_amdgcn_exp2f(x3);
      }
  }

  // add-butterfly across the 16 lanes of each group
  #pragma unroll
  for (int mf = 0; mf < 4; ++mf)
    #pragma unroll
    for (int rr = 0; rr < 4; ++rr) {
      float s_ = rsum[mf][rr];
      #pragma unroll
      for (int o = 1; o < 16; o <<= 1) s_ += __shfl_xor(s_, o);
      if (lr == 0) ws_s[wid][mf * 16 + g * 4 + rr] = s_;
    }
  __syncthreads();
  if (tid < JROWS) {
    int bo = bld_off[tid];
    if (bo >= 0) {
      float S = 0.f;
      #pragma unroll
      for (int w = 0; w < 8; ++w) S += ws_s[w][tid];
      float lse2v = __builtin_amdgcn_logf(S);   // log2
      Z[bo] = l0_s[tid] - lse2v;                // LOG2 DOMAIN, blank slot
      int eo = eld_off[tid];
      if (eo >= 0) Z[eo] = lt_s[tid] - lse2v;   // emit slot
    }
  }
}

// ---------------- Kernel 3: alpha DP — float4 operand quads (r12) -----------
#define ACH 8
#define NCH 48   /* s1 reaches 383 >= dstar max 379; slack rows cover tail */
__global__ __launch_bounds__(256) void alpha_kernel(
    const float* __restrict__ Z,
    const int* __restrict__ ilen, const int* __restrict__ ulen_,
    float* __restrict__ out) {
  __shared__ float lls[B_DIM];
  const int tid = threadIdx.x;
  const int b = tid >> 6;
  const int lane = tid & 63;
  const float NEG = NEGF;
  const int tl = ilen[b], ul = ulen_[b];
  const int dstar = tl - 1 + ul;          // final-cell diagonal

  const int u0 = lane;           // slot 0: u = 0..63
  const int u1 = 64 + lane;      // slot 1: u = 64..80 (lane < 17)
  const bool act1 = (u1 <= 80);
  const int uc1 = act1 ? u1 : 80;

  const float* Zb = Z + (size_t)b * (NDIAG * ZSTR);

  f32x4 Aq0[ACH], Aq1[ACH], Bq0[ACH], Bq1[ACH];

  #define ALOAD(P, c)                                                        \
    {                                                                        \
      const float* base0 = Zb + (c) * (ACH * ZSTR) + 1 + 2 * u0;             \
      const float* base1 = Zb + (c) * (ACH * ZSTR) + 1 + 2 * uc1;            \
      _Pragma("unroll")                                                      \
      for (int j = 0; j < ACH; ++j) {                                        \
        P##q0[j] = load4u(base0 + j * ZSTR);                                 \
        P##q1[j] = load4u(base1 + j * ZSTR);                                 \
      }                                                                      \
    }

  #define ACOMP(P, c)                                                        \
    {                                                                        \
      _Pragma("unroll")                                                      \
      for (int q = 0; q < ACH / 2; ++q) {                                    \
        const int j = 2 * q;                                                 \
        const int s1 = (c) * ACH + j + 1;                                    \
        /* neighbor alphas via DPP (VALU pipe) */                            \
        float a63 = readlanef(pa0, 63), a62 = readlanef(pa0, 62);            \
        float s0m1 = ror1f(pa0);                                             \
        float s0m2 = ror1f(s0m1);                                            \
        float s1m1r = ror1f(pa1);                                            \
        float s1m2r = ror1f(s1m1r);                                          \
        float s1m1 = (lane == 0) ? a63 : s1m1r;                              \
        float s1m2 = (lane == 0) ? a62 : ((lane == 1) ? a63 : s1m2r);        \
        float na0, na1;                                                      \
        { /* slot 0 — v={e1m,b1m,e1,b1}, w=next row */                       \
          f32x4 v = P##q0[j], w = P##q0[j + 1];                              \
          float T1 = v[3] + w[3];                                            \
          float T2 = lse2_2(v[2] + w[3], v[1] + w[2]);                       \
          float T3 = v[0] + w[2];                                            \
          float p0 = pa0 + T1;                                               \
          float p1 = s0m1 + T2;                                              \
          float p2 = s0m2 + T3;                                              \
          float mx = fmaxf(fmaxf(p0, p1), p2);                               \
          float ss = __builtin_amdgcn_exp2f(p0 - mx)                         \
                   + __builtin_amdgcn_exp2f(p1 - mx)                         \
                   + __builtin_amdgcn_exp2f(p2 - mx);                        \
          na0 = fmaxf(mx + __builtin_amdgcn_logf(ss), NEG);                  \
        }                                                                    \
        { /* slot 1 */                                                       \
          f32x4 v = P##q1[j], w = P##q1[j + 1];                              \
          float T1 = v[3] + w[3];                                            \
          float T2 = lse2_2(v[2] + w[3], v[1] + w[2]);                       \
          float T3 = v[0] + w[2];                                            \
          float p0 = pa1 + T1;                                               \
          float p1 = s1m1 + T2;                                              \
          float p2 = s1m2 + T3;                                              \
          float mx = fmaxf(fmaxf(p0, p1), p2);                               \
          float ss = __builtin_amdgcn_exp2f(p0 - mx)                         \
                   + __builtin_amdgcn_exp2f(p1 - mx)                         \
                   + __builtin_amdgcn_exp2f(p2 - mx);                        \
          na1 = fmaxf(mx + __builtin_amdgcn_logf(ss), NEG);                  \
        }                                                                    \
        if (s1 == dstar) { /* odd-diagonal final capture */                  \
          float vo0 = lse2_2(pa0 + P##q0[j][3], s0m1 + P##q0[j][2]);         \
          if (u0 == ul) fin = vo0;                                           \
          float vo1 = lse2_2(pa1 + P##q1[j][3], s1m1 + P##q1[j][2]);         \
          if (act1 && u1 == ul) fin = vo1;                                   \
        }                                                                    \
        pa0 = na0; pa1 = na1;                                                \
        if (s1 + 1 == dstar) { /* even-diagonal final capture */             \
          if (u0 == ul) fin = pa0;                                           \
          if (act1 && u1 == ul) fin = pa1;                                   \
        }                                                                    \
      }                                                                      \
    }

  float pa0 = (u0 == 0) ? 0.f : NEG;  // alpha on diag 0 (log2 domain)
  float pa1 = NEG;
  float fin = NEG;
  if (dstar == 0 && u0 == ul) fin = pa0;   // tl=1, ul=0 corner

  ALOAD(A, 0);
  for (int p = 0; p < NCH / 2; ++p) {
    const int cA = 2 * p, cB = 2 * p + 1;
    ALOAD(B, cB);        // issue next chunk's loads (covered by ACOMP(A))
    ACOMP(A, cA);
    ALOAD(A, cA + 2);    // tail chunks read NEG slack rows — harmless
    ACOMP(B, cB);
  }

  #pragma unroll
  for (int o = 32; o; o >>= 1) fin = fmaxf(fin, __shfl_xor(fin, o));
  if (lane == 0) {
    float last = Zb[(size_t)dstar * ZSTR + 4 + 2 * ul];   // blank, log2 domain
    lls[b] = fin + last;
  }
  __syncthreads();
  if (tid == 0)
    out[0] = -(lls[0] + lls[1] + lls[2] + lls[3]) * (LN2 * 0.25f);
}

// ---------------- launcher ----------------
extern "C" void kernel_launch(void* const* d_in, const int* in_sizes, int n_in,
                              void* d_out, int out_size, void* d_ws, size_t ws_size,
                              hipStream_t stream) {
  const float* enc = (const float*)d_in[0];
  const float* dec = (const float*)d_in[1];
  const float* Wf  = (const float*)d_in[2];
  const float* bfv = (const float*)d_in[3];
  const float* Wp  = (const float*)d_in[4];
  const float* bp  = (const float*)d_in[5];
  const int* targets = (const int*)d_in[6];
  const int* ilen    = (const int*)d_in[7];
  const int* ulen    = (const int*)d_in[8];
  float* out = (float*)d_out;
  char* ws = (char*)d_ws;

  short* WfB = (short*)(ws + 0);          //   655360 B (packed)
  short* WpB = (short*)(ws + 655360);     //  1048576 B (packed) -> 1703936
  short* epB = (short*)(ws + 1703936);    //  1228800 B (bf16)   -> 2932736
  short* dpB = (short*)(ws + 2932736);    //   331776 B (bf16)   -> 3264512
  float* Z   = (float*)(ws + 3264512);    //  1026816 B (1528*168*4) -> 4291328

  // cvt+pack (832 blocks) fused with Z NEG-prefill (251 tail blocks)
  cvt_kernel<<<1083, 256, 0, stream>>>(Wf, Wp, WfB, WpB, Z);
  proj_kernel<<<50, 256, 0, stream>>>(enc, dec, WfB, bfv, epB, dpB);
  joint_kernel<<<(NROWS + JROWS - 1) / JROWS, 512, 65536, stream>>>(epB, dpB, WpB, bp, targets, Z);
  alpha_kernel<<<1, 256, 0, stream>>>(Z, ilen, ulen, out);
}